// Round 3
// baseline (3082.671 us; speedup 1.0000x reference)
//
#include <hip/hip_runtime.h>
#include <math.h>

#define B_ 2
#define V_ 6
#define C_ 256
#define P_ 200
#define H_ 8
#define D_ 32
#define L_ 2
#define F_ 1024
#define N_ 3520
#define HW0T 2816
#define HW1T 704
#define BV_ (B_*V_)
#define NKTOT (BV_*N_)
#define ROWS_ (BV_*P_)
#define BVH_ (BV_*H_)
#define NEGV -1000000000.0f

// ---------------- workspace offsets (in floats) ----------------
static const size_t O_KEYS = 0;                                  // 10813440
static const size_t O_CAM  = O_KEYS + (size_t)NKTOT*C_;          // 4055040
static const size_t O_PEK  = O_CAM  + (size_t)NKTOT*96;          // 10813440
static const size_t O_BIG  = O_PEK  + (size_t)NKTOT*C_;          // HID / KVP overlap (HID dead before KVP written)
static const size_t O_HID  = O_BIG;
static const size_t O_KVP  = O_BIG;                              // 21626880
static const size_t O_PEQH = O_BIG + (size_t)NKTOT*512;
static const size_t O_PEQ  = O_PEQH + 102400;
static const size_t O_X    = O_PEQ  + 102400;
static const size_t O_QKV  = O_X    + 614400;
static const size_t O_SAIN = O_QKV  + 614400;
static const size_t O_ATT  = O_SAIN + 1843200;
static const size_t O_QPROJ= O_ATT  + 614400;
static const size_t O_PROJ = O_QPROJ+ 614400;
static const size_t O_TMP  = O_PROJ + 614400;
static const size_t O_FFNH = O_TMP  + 614400;
static const size_t O_QF   = O_FFNH + 2457600;
static const size_t O_H1   = O_QF   + 102400;
static const size_t O_QPOS = O_H1   + 102400;
static const size_t O_ACTF = O_QPOS + 1200;
static const size_t O_ACTN = O_ACTF + 2400;
static const size_t O_INV  = O_ACTN + 2400;
static const size_t O_PML  = O_INV  + 192;
static const size_t O_PACC = O_PML  + 307200;
// end = O_PACC + 4915200 = 60934192 floats (~244 MB)

// ---------------- output offsets (floats) ----------------
#define OO_QFEAT   0
#define OO_QPOS    102400
#define OO_POSBEV  103600
#define OO_CENTERS 104400
#define OO_HEIGHTS 106000

// ============ 4x4 inverse (adjugate; row-major in/out) ============
__global__ void inv4_kernel(const float* __restrict__ A, float* __restrict__ Ainv) {
    int t = blockIdx.x * blockDim.x + threadIdx.x;
    if (t >= BV_) return;
    const float* m = A + t*16;
    float i0  =  m[5]*m[10]*m[15] - m[5]*m[11]*m[14] - m[9]*m[6]*m[15] + m[9]*m[7]*m[14] + m[13]*m[6]*m[11] - m[13]*m[7]*m[10];
    float i4  = -m[4]*m[10]*m[15] + m[4]*m[11]*m[14] + m[8]*m[6]*m[15] - m[8]*m[7]*m[14] - m[12]*m[6]*m[11] + m[12]*m[7]*m[10];
    float i8  =  m[4]*m[9]*m[15]  - m[4]*m[11]*m[13] - m[8]*m[5]*m[15] + m[8]*m[7]*m[13] + m[12]*m[5]*m[11] - m[12]*m[7]*m[9];
    float i12 = -m[4]*m[9]*m[14]  + m[4]*m[10]*m[13] + m[8]*m[5]*m[14] - m[8]*m[6]*m[13] - m[12]*m[5]*m[10] + m[12]*m[6]*m[9];
    float i1  = -m[1]*m[10]*m[15] + m[1]*m[11]*m[14] + m[9]*m[2]*m[15] - m[9]*m[3]*m[14] - m[13]*m[2]*m[11] + m[13]*m[3]*m[10];
    float i5  =  m[0]*m[10]*m[15] - m[0]*m[11]*m[14] - m[8]*m[2]*m[15] + m[8]*m[3]*m[14] + m[12]*m[2]*m[11] - m[12]*m[3]*m[10];
    float i9  = -m[0]*m[9]*m[15]  + m[0]*m[11]*m[13] + m[8]*m[1]*m[15] - m[8]*m[3]*m[13] - m[12]*m[1]*m[11] + m[12]*m[3]*m[9];
    float i13 =  m[0]*m[9]*m[14]  - m[0]*m[10]*m[13] - m[8]*m[1]*m[14] + m[8]*m[2]*m[13] + m[12]*m[1]*m[10] - m[12]*m[2]*m[9];
    float i2  =  m[1]*m[6]*m[15]  - m[1]*m[7]*m[14]  - m[5]*m[2]*m[15] + m[5]*m[3]*m[14] + m[13]*m[2]*m[7]  - m[13]*m[3]*m[6];
    float i6  = -m[0]*m[6]*m[15]  + m[0]*m[7]*m[14]  + m[4]*m[2]*m[15] - m[4]*m[3]*m[14] - m[12]*m[2]*m[7]  + m[12]*m[3]*m[6];
    float i10 =  m[0]*m[5]*m[15]  - m[0]*m[7]*m[13]  - m[4]*m[1]*m[15] + m[4]*m[3]*m[13] + m[12]*m[1]*m[7]  - m[12]*m[3]*m[5];
    float i14 = -m[0]*m[5]*m[14]  + m[0]*m[6]*m[13]  + m[4]*m[1]*m[14] - m[4]*m[2]*m[13] - m[12]*m[1]*m[6]  + m[12]*m[2]*m[5];
    float i3  = -m[1]*m[6]*m[11]  + m[1]*m[7]*m[10]  + m[5]*m[2]*m[11] - m[5]*m[3]*m[10] - m[9]*m[2]*m[7]   + m[9]*m[3]*m[6];
    float i7  =  m[0]*m[6]*m[11]  - m[0]*m[7]*m[10]  - m[4]*m[2]*m[11] + m[4]*m[3]*m[10] + m[8]*m[2]*m[7]   - m[8]*m[3]*m[6];
    float i11 = -m[0]*m[5]*m[11]  + m[0]*m[7]*m[9]   + m[4]*m[1]*m[11] - m[4]*m[3]*m[9]  - m[8]*m[1]*m[7]   + m[8]*m[3]*m[5];
    float i15 =  m[0]*m[5]*m[10]  - m[0]*m[6]*m[9]   - m[4]*m[1]*m[10] + m[4]*m[2]*m[9]  + m[8]*m[1]*m[6]   - m[8]*m[2]*m[5];
    float det = m[0]*i0 + m[1]*i4 + m[2]*i8 + m[3]*i12;
    float r = 1.0f / det;
    float* o = Ainv + t*16;
    o[0]=i0*r;  o[1]=i1*r;  o[2]=i2*r;  o[3]=i3*r;
    o[4]=i4*r;  o[5]=i5*r;  o[6]=i6*r;  o[7]=i7*r;
    o[8]=i8*r;  o[9]=i9*r;  o[10]=i10*r;o[11]=i11*r;
    o[12]=i12*r;o[13]=i13*r;o[14]=i14*r;o[15]=i15*r;
}

// ============ cam features: (B,V,N,D*3) ============
__global__ void cam_kernel(const float* __restrict__ pos, const int* __restrict__ hw,
                           const float* __restrict__ inv, float* __restrict__ cam) {
    int g = blockIdx.x * blockDim.x + threadIdx.x;
    const int total = BV_ * N_ * D_;
    if (g >= total) return;
    int d  = g & 31;
    int n  = (g >> 5) % N_;
    int bv = g / (N_ * D_);
    int b  = bv / V_;
    float sx = pos[n*2+0], sy = pos[n*2+1];
    float mx = (float)hw[b*2+1], my = (float)hw[b*2+0];
    float px = mx / (1.0f + expf(-sx));
    float py = my / (1.0f + expf(-sy));
    const float binsz = 53.0f / 1056.0f;
    float cd = fmaxf(1.0f + binsz * (float)d * (float)(d+1), 1e-5f);
    float h0 = px*cd, h1 = py*cd, h2 = cd, h3 = 1.0f;
    const float* iv = inv + bv*16;
    float* o = cam + ((size_t)bv * N_ + n) * 96 + d*3;
    o[0] = iv[0]*h0 + iv[1]*h1 + iv[2]*h2  + iv[3]*h3;
    o[1] = iv[4]*h0 + iv[5]*h1 + iv[6]*h2  + iv[7]*h3;
    o[2] = iv[8]*h0 + iv[9]*h1 + iv[10]*h2 + iv[11]*h3;
}

// ============ keys: transpose (BV,C,HW) slab -> keys[bv][n_off+hw][c] ============
__global__ void transpose_keys_kernel(const float* __restrict__ src, float* __restrict__ keys,
                                      int HW, int n_off) {
    __shared__ float tile[32][33];
    int bv = blockIdx.z;
    int x0 = blockIdx.x * 32;   // hw
    int c0 = blockIdx.y * 32;   // channel
    int tx = threadIdx.x, ty = threadIdx.y;
    tile[ty][tx] = src[((size_t)bv * C_ + c0 + ty) * HW + x0 + tx];
    __syncthreads();
    keys[((size_t)bv * N_ + n_off + x0 + ty) * C_ + c0 + tx] = tile[tx][ty];
}

// ============ active mask ============
__global__ void mask_kernel(const int* __restrict__ qvm, float* __restrict__ actF, float* __restrict__ actNeg) {
    int bv = blockIdx.x;
    int b = bv / V_, v = bv % V_;
    int p = threadIdx.x;
    int m = 0;
    if (p < P_) m = (qvm[(b*P_ + p)*V_ + v] > 0) ? 1 : 0;
    __shared__ int s[256];
    s[threadIdx.x] = m;
    __syncthreads();
    for (int off = 128; off > 0; off >>= 1) {
        if (threadIdx.x < off) s[threadIdx.x] += s[threadIdx.x + off];
        __syncthreads();
    }
    int valid = (s[0] > 1);
    if (p < P_) {
        int act = m && valid;
        actF[bv*P_ + p]   = act ? 1.0f : 0.0f;
        actNeg[bv*P_ + p] = act ? 0.0f : NEGV;
    }
}

// ============ generic GEMM: C[M,N] = act(A(+A2) @ W^T + bias) ============
// A (M,K) row-major, W (N,K) row-major.
template<int RELU, int FUSE>
__global__ __launch_bounds__(256) void gemm_kernel(
    const float* __restrict__ A, const float* __restrict__ A2,
    const float* __restrict__ W, const float* __restrict__ bias,
    float* __restrict__ Cmat, int M, int N, int K)
{
    __shared__ float As[16][68];
    __shared__ float Ws[16][68];
    int m0 = blockIdx.y * 64, n0 = blockIdx.x * 64;
    int tid = threadIdx.x;
    int tx = tid & 15, ty = tid >> 4;
    int ar = tid >> 2;
    int ac = (tid & 3) * 4;
    float acc[4][4] = {};
    for (int k0 = 0; k0 < K; k0 += 16) {
        #pragma unroll
        for (int j = 0; j < 4; ++j) {
            int kk = ac + j;
            int m = m0 + ar;
            float v = 0.0f;
            if (m < M && (k0 + kk) < K) {
                v = A[(size_t)m * K + k0 + kk];
                if (FUSE) v += A2[(size_t)m * K + k0 + kk];
            }
            As[kk][ar] = v;
        }
        #pragma unroll
        for (int j = 0; j < 4; ++j) {
            int kk = ac + j;
            int n = n0 + ar;
            float v = 0.0f;
            if (n < N && (k0 + kk) < K) v = W[(size_t)n * K + k0 + kk];
            Ws[kk][ar] = v;
        }
        __syncthreads();
        #pragma unroll
        for (int kk = 0; kk < 16; ++kk) {
            const float4 a = *(const float4*)&As[kk][ty*4];
            const float4 w = *(const float4*)&Ws[kk][tx*4];
            acc[0][0] = fmaf(a.x, w.x, acc[0][0]); acc[0][1] = fmaf(a.x, w.y, acc[0][1]);
            acc[0][2] = fmaf(a.x, w.z, acc[0][2]); acc[0][3] = fmaf(a.x, w.w, acc[0][3]);
            acc[1][0] = fmaf(a.y, w.x, acc[1][0]); acc[1][1] = fmaf(a.y, w.y, acc[1][1]);
            acc[1][2] = fmaf(a.y, w.z, acc[1][2]); acc[1][3] = fmaf(a.y, w.w, acc[1][3]);
            acc[2][0] = fmaf(a.z, w.x, acc[2][0]); acc[2][1] = fmaf(a.z, w.y, acc[2][1]);
            acc[2][2] = fmaf(a.z, w.z, acc[2][2]); acc[2][3] = fmaf(a.z, w.w, acc[2][3]);
            acc[3][0] = fmaf(a.w, w.x, acc[3][0]); acc[3][1] = fmaf(a.w, w.y, acc[3][1]);
            acc[3][2] = fmaf(a.w, w.z, acc[3][2]); acc[3][3] = fmaf(a.w, w.w, acc[3][3]);
        }
        __syncthreads();
    }
    #pragma unroll
    for (int i = 0; i < 4; ++i) {
        int m = m0 + ty*4 + i;
        if (m >= M) continue;
        #pragma unroll
        for (int j = 0; j < 4; ++j) {
            int n = n0 + tx*4 + j;
            if (n >= N) continue;
            float v = acc[i][j] + bias[n];
            if (RELU) v = fmaxf(v, 0.0f);
            Cmat[(size_t)m * N + n] = v;
        }
    }
}

// ============ LayerNorm over C=256 of (a+b), wave per row ============
__global__ __launch_bounds__(256) void ln_kernel(const float* __restrict__ Xa, const float* __restrict__ Xb,
    const float* __restrict__ g, const float* __restrict__ beta, float* __restrict__ out, int rows)
{
    int wid  = (blockIdx.x * blockDim.x + threadIdx.x) >> 6;
    int lane = threadIdx.x & 63;
    if (wid >= rows) return;
    float4 x = ((const float4*)(Xa + (size_t)wid * C_))[lane];
    float4 y = ((const float4*)(Xb + (size_t)wid * C_))[lane];
    x.x += y.x; x.y += y.y; x.z += y.z; x.w += y.w;
    float s = x.x + x.y + x.z + x.w;
    for (int d = 32; d > 0; d >>= 1) s += __shfl_xor(s, d);
    float mean = s * (1.0f / C_);
    float dx = x.x - mean, dy = x.y - mean, dz = x.z - mean, dw = x.w - mean;
    float v = dx*dx + dy*dy + dz*dz + dw*dw;
    for (int d = 32; d > 0; d >>= 1) v += __shfl_xor(v, d);
    float rstd = 1.0f / sqrtf(v * (1.0f / C_) + 1e-5f);
    float4 gg = ((const float4*)g)[lane];
    float4 bb = ((const float4*)beta)[lane];
    float4 o;
    o.x = dx * rstd * gg.x + bb.x;
    o.y = dy * rstd * gg.y + bb.y;
    o.z = dz * rstd * gg.z + bb.z;
    o.w = dw * rstd * gg.w + bb.w;
    ((float4*)(out + (size_t)wid * C_))[lane] = o;
}

// ============ x broadcast: q_feat (B,C,P) -> x (B,V,P,C) ============
__global__ void xbcast_kernel(const float* __restrict__ qf, float* __restrict__ x) {
    __shared__ float tile[32][33];
    int b  = blockIdx.z;
    int p0 = blockIdx.x * 32, c0 = blockIdx.y * 32;
    int tx = threadIdx.x, ty = threadIdx.y;
    float v = 0.0f;
    if (p0 + tx < P_) v = qf[((size_t)b * C_ + c0 + ty) * P_ + p0 + tx];
    tile[ty][tx] = v;
    __syncthreads();
    int p = p0 + ty;
    if (p < P_) {
        float val = tile[tx][ty];
        #pragma unroll
        for (int vv = 0; vv < V_; ++vv)
            x[(((size_t)(b*V_ + vv) * P_) + p) * C_ + c0 + tx] = val;
    }
}

// ============ out = x + broadcast_over_V(peq) ============
__global__ void bcast_add_kernel(const float* __restrict__ x, const float* __restrict__ peq, float* __restrict__ out) {
    int g = blockIdx.x * blockDim.x + threadIdx.x;   // float4 index
    const int total = ROWS_ * C_ / 4;
    if (g >= total) return;
    int c4 = g & 63;
    int rest = g >> 6;            // (b*V+v)*P + p
    int p  = rest % P_;
    int bv = rest / P_;
    int b  = bv / V_;
    float4 xv = ((const float4*)x)[g];
    float4 pv = ((const float4*)peq)[((size_t)(b*P_ + p)) * 64 + c4];
    float4 o; o.x = xv.x + pv.x; o.y = xv.y + pv.y; o.z = xv.z + pv.z; o.w = xv.w + pv.w;
    ((float4*)out)[g] = o;
}

// ============ attention: thread = one query row, keys split across blocks ============
__global__ __launch_bounds__(256) void attn_kernel(
    const float* __restrict__ Q, int qstride,
    const float* __restrict__ Kp, int kstride,
    const float* __restrict__ Vp, int vstride,
    const float* __restrict__ biasNeg,      // null or actNeg per (bv, key); key dim == P_
    float* __restrict__ pAcc, float* __restrict__ pML,
    int NK, int S, float scale)
{
    int split = blockIdx.x, bvh = blockIdx.y;
    int bv = bvh >> 3, h = bvh & 7;
    int p = threadIdx.x;
    bool act = p < P_;
    int per = (NK + S - 1) / S;
    int k0 = split * per;
    int k1 = min(NK, k0 + per);

    __shared__ float Ks[32][36];
    __shared__ float Vs[32][36];
    __shared__ float Bs[32];

    float q[32];
    const float* qrow = Q + ((size_t)bv * P_ + (act ? p : 0)) * qstride + h * 32;
    #pragma unroll
    for (int j = 0; j < 32; j += 4) {
        float4 t = *(const float4*)(qrow + j);
        q[j] = t.x; q[j+1] = t.y; q[j+2] = t.z; q[j+3] = t.w;
    }
    float m = -INFINITY, l = 0.0f;
    float acc[32] = {};

    for (int kt = k0; kt < k1; kt += 32) {
        int kmax = min(32, k1 - kt);
        __syncthreads();
        {
            int t = threadIdx.x;
            int key = t >> 3, f = (t & 7) << 2;
            if (key < kmax) {
                const float* kr = Kp + ((size_t)bv * NK + kt + key) * kstride + h*32 + f;
                *(float4*)&Ks[key][f] = *(const float4*)kr;
                const float* vr = Vp + ((size_t)bv * NK + kt + key) * vstride + h*32 + f;
                *(float4*)&Vs[key][f] = *(const float4*)vr;
            }
            if (t < kmax) Bs[t] = biasNeg ? biasNeg[bv * P_ + kt + t] : 0.0f;
        }
        __syncthreads();
        if (act) {
            for (int k = 0; k < kmax; ++k) {
                const float4* k4 = (const float4*)&Ks[k][0];
                float s0 = 0, s1 = 0, s2 = 0, s3 = 0;
                #pragma unroll
                for (int jj = 0; jj < 8; ++jj) {
                    float4 kv = k4[jj];
                    s0 = fmaf(q[4*jj+0], kv.x, s0);
                    s1 = fmaf(q[4*jj+1], kv.y, s1);
                    s2 = fmaf(q[4*jj+2], kv.z, s2);
                    s3 = fmaf(q[4*jj+3], kv.w, s3);
                }
                float s = ((s0 + s1) + (s2 + s3)) * scale + Bs[k];
                const float4* v4 = (const float4*)&Vs[k][0];
                if (__any(s > m)) {
                    float mn = fmaxf(m, s);
                    float corr = __expf(m - mn);
                    float pr = __expf(s - mn);
                    m = mn;
                    l = fmaf(l, corr, pr);
                    #pragma unroll
                    for (int jj = 0; jj < 8; ++jj) {
                        float4 vv = v4[jj];
                        acc[4*jj+0] = fmaf(acc[4*jj+0], corr, pr * vv.x);
                        acc[4*jj+1] = fmaf(acc[4*jj+1], corr, pr * vv.y);
                        acc[4*jj+2] = fmaf(acc[4*jj+2], corr, pr * vv.z);
                        acc[4*jj+3] = fmaf(acc[4*jj+3], corr, pr * vv.w);
                    }
                } else {
                    float pr = __expf(s - m);
                    l += pr;
                    #pragma unroll
                    for (int jj = 0; jj < 8; ++jj) {
                        float4 vv = v4[jj];
                        acc[4*jj+0] = fmaf(pr, vv.x, acc[4*jj+0]);
                        acc[4*jj+1] = fmaf(pr, vv.y, acc[4*jj+1]);
                        acc[4*jj+2] = fmaf(pr, vv.z, acc[4*jj+2]);
                        acc[4*jj+3] = fmaf(pr, vv.w, acc[4*jj+3]);
                    }
                }
            }
        }
    }
    if (act) {
        size_t base = ((size_t)bvh * S + split) * 32 * P_ + p;
        #pragma unroll
        for (int j = 0; j < 32; ++j) pAcc[base + (size_t)j * P_] = acc[j];
        size_t mb = ((size_t)bvh * S + split) * 2 * P_ + p;
        pML[mb] = m; pML[mb + P_] = l;
    }
}

// ============ combine split partials ============
template<int S>
__global__ void attn_combine_kernel(const float* __restrict__ pAcc, const float* __restrict__ pML,
                                    float* __restrict__ Out)
{
    int g = blockIdx.x * blockDim.x + threadIdx.x;
    if (g >= BVH_ * P_) return;
    int p = g % P_;
    int bvh = g / P_;
    int bv = bvh >> 3, h = bvh & 7;
    float mg = -INFINITY;
    #pragma unroll
    for (int s = 0; s < S; ++s) mg = fmaxf(mg, pML[((size_t)bvh * S + s) * 2 * P_ + p]);
    float w[S];
    float L = 0.0f;
    #pragma unroll
    for (int s = 0; s < S; ++s) {
        float ms = pML[((size_t)bvh * S + s) * 2 * P_ + p];
        float ls = pML[((size_t)bvh * S + s) * 2 * P_ + P_ + p];
        float ws = __expf(ms - mg);
        w[s] = ws;
        L = fmaf(ls, ws, L);
    }
    float invL = 1.0f / L;
    float* orow = Out + ((size_t)bv * P_ + p) * C_ + h * 32;
    #pragma unroll
    for (int j = 0; j < 32; ++j) {
        float acc = 0.0f;
        #pragma unroll
        for (int s = 0; s < S; ++s)
            acc = fmaf(pAcc[(((size_t)bvh * S + s) * 32 + j) * P_ + p], w[s], acc);
        orow[j] = acc * invL;
    }
}

// ============ aggregation: masked mean over views -> q_feat (B,C,P) ============
__global__ void agg_kernel(const float* __restrict__ x, const float* __restrict__ actF,
                           float* __restrict__ qf, float* __restrict__ qf_out) {
    int bp = blockIdx.x;
    int b = bp / P_, p = bp % P_;
    int c = threadIdx.x;
    float sum = 0.0f, cnt = 0.0f;
    #pragma unroll
    for (int v = 0; v < V_; ++v) {
        float a = actF[(b*V_ + v) * P_ + p];
        cnt += a;
        sum = fmaf(a, x[(((size_t)(b*V_ + v)) * P_ + p) * C_ + c], sum);
    }
    float r = sum / (cnt + 1e-4f);
    qf[((size_t)b * C_ + c) * P_ + p] = r;
    if (qf_out) qf_out[((size_t)b * C_ + c) * P_ + p] = r;
}

// ============ head layer 1: h1[b,o,p] = relu(w1[o,:] . qf[b,:,p] + b1[o]) ============
__global__ void head1_kernel(const float* __restrict__ w1, const float* __restrict__ b1,
                             const float* __restrict__ qf, float* __restrict__ h1out) {
    int g = blockIdx.x * blockDim.x + threadIdx.x;
    if (g >= B_ * C_ * P_) return;
    int p = g % P_;
    int o = (g / P_) % C_;
    int b = g / (P_ * C_);
    float s = b1[o];
    const float* wr = w1 + (size_t)o * C_;
    const float* qc = qf + (size_t)b * C_ * P_ + p;
    for (int c = 0; c < C_; ++c) s = fmaf(wr[c], qc[(size_t)c * P_], s);
    h1out[g] = fmaxf(s, 0.0f);
}

// ============ head layer 2 + center/bev/height outputs ============
__global__ void center_kernel(const float* __restrict__ w2, const float* __restrict__ b2,
                              const float* __restrict__ h1, const float* __restrict__ qpos_in,
                              float* __restrict__ qpos_ws, float* __restrict__ out, int layer) {
    int g = blockIdx.x * blockDim.x + threadIdx.x;
    if (g >= B_ * P_) return;
    int p = g % P_, b = g / P_;
    float c0 = b2[0], c1 = b2[1], c2 = b2[2];
    const float* hc = h1 + (size_t)b * C_ * P_ + p;
    for (int c = 0; c < C_; ++c) {
        float hv = hc[(size_t)c * P_];
        c0 = fmaf(w2[c], hv, c0);
        c1 = fmaf(w2[C_ + c], hv, c1);
        c2 = fmaf(w2[2*C_ + c], hv, c2);
    }
    const float* qp = qpos_in + ((size_t)b * P_ + p) * 3;
    c0 += qp[0]; c1 += qp[1]; c2 += qp[2];
    float* qw = qpos_ws + ((size_t)b * P_ + p) * 3;
    qw[0] = c0; qw[1] = c1; qw[2] = c2;
    float cx = (c0 + 54.0f) / 108.0f * 180.0f;
    float cy = (c1 + 54.0f) / 108.0f * 180.0f;
    float* centers = out + OO_CENTERS + ((size_t)(layer * B_ + b) * 2) * P_;
    centers[p] = cx;
    centers[P_ + p] = cy;
    out[OO_HEIGHTS + (size_t)(layer * B_ + b) * P_ + p] = c2;
    if (layer == L_ - 1) {
        float* qo = out + OO_QPOS + ((size_t)b * P_ + p) * 3;
        qo[0] = c0; qo[1] = c1; qo[2] = c2;
        float* pb = out + OO_POSBEV + ((size_t)b * P_ + p) * 2;
        pb[0] = cx; pb[1] = cy;
    }
}

// =====================================================================
extern "C" void kernel_launch(void* const* d_in, const int* in_sizes, int n_in,
                              void* d_out, int out_size, void* d_ws, size_t ws_size,
                              hipStream_t stream) {
    const float* in_qfeat = (const float*)d_in[0];
    const float* in_qpos  = (const float*)d_in[1];
    const int*   in_qvm   = (const int*)d_in[2];
    const float* in_f0    = (const float*)d_in[3];
    const float* in_f1    = (const float*)d_in[4];
    const float* in_pos   = (const float*)d_in[5];
    const float* in_l2i   = (const float*)d_in[6];
    const int*   in_hw    = (const int*)d_in[7];
    const float* qpos_w1  = (const float*)d_in[8];
    const float* qpos_b1  = (const float*)d_in[9];
    const float* qpos_w2  = (const float*)d_in[10];
    const float* qpos_b2  = (const float*)d_in[11];
    const float* kpos_w1  = (const float*)d_in[12];
    const float* kpos_b1  = (const float*)d_in[13];
    const float* kpos_w2  = (const float*)d_in[14];
    const float* kpos_b2  = (const float*)d_in[15];
    const float* sa_in_w  = (const float*)d_in[16];
    const float* sa_in_b  = (const float*)d_in[17];
    const float* sa_out_w = (const float*)d_in[18];
    const float* sa_out_b = (const float*)d_in[19];
    const float* ca_in_w  = (const float*)d_in[20];
    const float* ca_in_b  = (const float*)d_in[21];
    const float* ca_out_w = (const float*)d_in[22];
    const float* ca_out_b = (const float*)d_in[23];
    const float* ffn_w1   = (const float*)d_in[24];
    const float* ffn_b1   = (const float*)d_in[25];
    const float* ffn_w2   = (const float*)d_in[26];
    const float* ffn_b2   = (const float*)d_in[27];
    const float* n1_g     = (const float*)d_in[28];
    const float* n1_b     = (const float*)d_in[29];
    const float* n2_g     = (const float*)d_in[30];
    const float* n2_b     = (const float*)d_in[31];
    const float* n3_g     = (const float*)d_in[32];
    const float* n3_b     = (const float*)d_in[33];
    const float* head_w1  = (const float*)d_in[34];
    const float* head_b1  = (const float*)d_in[35];
    const float* head_w2  = (const float*)d_in[36];
    const float* head_b2  = (const float*)d_in[37];

    float* ws   = (float*)d_ws;
    float* KEYS = ws + O_KEYS;
    float* CAM  = ws + O_CAM;
    float* PEK  = ws + O_PEK;
    float* HID  = ws + O_HID;
    float* KVP  = ws + O_KVP;
    float* PEQH = ws + O_PEQH;
    float* PEQ  = ws + O_PEQ;
    float* X    = ws + O_X;
    float* QKV  = ws + O_QKV;
    float* SAIN = ws + O_SAIN;
    float* ATT  = ws + O_ATT;
    float* QPROJ= ws + O_QPROJ;
    float* PROJ = ws + O_PROJ;
    float* TMP  = ws + O_TMP;
    float* FFNH = ws + O_FFNH;
    float* QF   = ws + O_QF;
    float* H1   = ws + O_H1;
    float* QPOS = ws + O_QPOS;
    float* ACTF = ws + O_ACTF;
    float* ACTN = ws + O_ACTN;
    float* INV  = ws + O_INV;
    float* PML  = ws + O_PML;
    float* PACC = ws + O_PACC;
    float* OUT  = (float*)d_out;

    const float scale = 0.17677669529663687f;   // 1/sqrt(32)

    // ---- one-time precompute ----
    inv4_kernel<<<1, 64, 0, stream>>>(in_l2i, INV);
    cam_kernel<<<(BV_*N_*D_ + 255)/256, 256, 0, stream>>>(in_pos, in_hw, INV, CAM);
    transpose_keys_kernel<<<dim3(HW0T/32, C_/32, BV_), dim3(32,32), 0, stream>>>(in_f0, KEYS, HW0T, 0);
    transpose_keys_kernel<<<dim3(HW1T/32, C_/32, BV_), dim3(32,32), 0, stream>>>(in_f1, KEYS, HW1T, HW0T);
    mask_kernel<<<BV_, 256, 0, stream>>>(in_qvm, ACTF, ACTN);

    for (int l = 0; l < L_; ++l) {
        const float* qf_src   = (l == 0) ? in_qfeat : QF;
        const float* qpos_src = (l == 0) ? in_qpos  : QPOS;

        // pe_q MLP (B*P=400 rows): 3 -> 256 relu -> 256
        gemm_kernel<1,0><<<dim3(4,7), 256, 0, stream>>>(qpos_src, nullptr, qpos_w1 + l*C_*3, qpos_b1 + l*C_, PEQH, 400, C_, 3);
        gemm_kernel<0,0><<<dim3(4,7), 256, 0, stream>>>(PEQH, nullptr, qpos_w2 + l*C_*C_, qpos_b2 + l*C_, PEQ, 400, C_, C_);

        // pe_k MLP (42240 rows): 96 -> 256 relu -> 256
        gemm_kernel<1,0><<<dim3(4,660), 256, 0, stream>>>(CAM, nullptr, kpos_w1 + l*C_*96, kpos_b1 + l*C_, HID, NKTOT, C_, 96);
        gemm_kernel<0,0><<<dim3(4,660), 256, 0, stream>>>(HID, nullptr, kpos_w2 + l*C_*C_, kpos_b2 + l*C_, PEK, NKTOT, C_, C_);

        // x = broadcast(q_feat); qkv = x + pe_q
        xbcast_kernel<<<dim3(7, 8, B_), dim3(32,32), 0, stream>>>(qf_src, X);
        bcast_add_kernel<<<600, 256, 0, stream>>>(X, PEQ, QKV);

        // --- self attention ---
        gemm_kernel<0,0><<<dim3(12,38), 256, 0, stream>>>(QKV, nullptr, sa_in_w + l*768*C_, sa_in_b + l*768, SAIN, ROWS_, 768, C_);
        attn_kernel<<<dim3(4, BVH_), 256, 0, stream>>>(SAIN, 768, SAIN + 256, 768, SAIN + 512, 768, ACTN, PACC, PML, P_, 4, scale);
        attn_combine_kernel<4><<<(BVH_*P_)/256, 256, 0, stream>>>(PACC, PML, ATT);
        gemm_kernel<0,0><<<dim3(4,38), 256, 0, stream>>>(ATT, nullptr, sa_out_w + l*C_*C_, sa_out_b + l*C_, PROJ, ROWS_, C_, C_);
        ln_kernel<<<600, 256, 0, stream>>>(X, PROJ, n1_g + l*C_, n1_b + l*C_, X, ROWS_);

        // --- cross attention ---
        bcast_add_kernel<<<600, 256, 0, stream>>>(X, PEQ, TMP);
        gemm_kernel<0,0><<<dim3(4,38), 256, 0, stream>>>(TMP, nullptr, ca_in_w + l*768*C_, ca_in_b + l*768, QPROJ, ROWS_, C_, C_);
        // kv = keys + pe_k fused; K/V projection -> (42240, 512)
        gemm_kernel<0,1><<<dim3(8,660), 256, 0, stream>>>(KEYS, PEK, ca_in_w + l*768*C_ + C_*C_, ca_in_b + l*768 + C_, KVP, NKTOT, 512, C_);
        attn_kernel<<<dim3(8, BVH_), 256, 0, stream>>>(QPROJ, 256, KVP, 512, KVP + 256, 512, nullptr, PACC, PML, N_, 8, scale);
        attn_combine_kernel<8><<<(BVH_*P_)/256, 256, 0, stream>>>(PACC, PML, ATT);
        gemm_kernel<0,0><<<dim3(4,38), 256, 0, stream>>>(ATT, nullptr, ca_out_w + l*C_*C_, ca_out_b + l*C_, PROJ, ROWS_, C_, C_);
        ln_kernel<<<600, 256, 0, stream>>>(X, PROJ, n2_g + l*C_, n2_b + l*C_, X, ROWS_);

        // --- FFN ---
        gemm_kernel<1,0><<<dim3(16,38), 256, 0, stream>>>(X, nullptr, ffn_w1 + l*F_*C_, ffn_b1 + l*F_, FFNH, ROWS_, F_, C_);
        gemm_kernel<0,0><<<dim3(4,38), 256, 0, stream>>>(FFNH, nullptr, ffn_w2 + l*C_*F_, ffn_b2 + l*C_, PROJ, ROWS_, C_, F_);
        ln_kernel<<<600, 256, 0, stream>>>(X, PROJ, n3_g + l*C_, n3_b + l*C_, X, ROWS_);

        // --- aggregate over views -> q_feat (B,C,P) ---
        agg_kernel<<<B_*P_, 256, 0, stream>>>(X, ACTF, QF, (l == L_-1) ? (OUT + OO_QFEAT) : nullptr);

        // --- head: centers / heights / q_pos update ---
        head1_kernel<<<(B_*C_*P_ + 255)/256, 256, 0, stream>>>(head_w1, head_b1, QF, H1);
        center_kernel<<<(B_*P_ + 255)/256, 256, 0, stream>>>(head_w2, head_b2, H1, qpos_src, QPOS, OUT, l);
    }
}

// Round 4
// 2054.384 us; speedup vs baseline: 1.5005x; 1.5005x over previous
//
#include <hip/hip_runtime.h>
#include <math.h>

#define B_ 2
#define V_ 6
#define C_ 256
#define P_ 200
#define H_ 8
#define D_ 32
#define L_ 2
#define F_ 1024
#define N_ 3520
#define HW0T 2816
#define HW1T 704
#define BV_ (B_*V_)
#define NKTOT (BV_*N_)
#define ROWS_ (BV_*P_)
#define BVH_ (BV_*H_)
#define NEGV -1000000000.0f

// ---------------- workspace offsets (in floats) ----------------
static const size_t O_KEYS = 0;
static const size_t O_CAM  = O_KEYS + (size_t)NKTOT*C_;
static const size_t O_PEK  = O_CAM  + (size_t)NKTOT*96;
static const size_t O_BIG  = O_PEK  + (size_t)NKTOT*C_;   // HID / KVP overlap (HID dead before KVP written)
static const size_t O_HID  = O_BIG;
static const size_t O_KVP  = O_BIG;
static const size_t O_PEQH = O_BIG + (size_t)NKTOT*512;
static const size_t O_PEQ  = O_PEQH + 102400;
static const size_t O_X    = O_PEQ  + 102400;
static const size_t O_QKV  = O_X    + 614400;
static const size_t O_SAIN = O_QKV  + 614400;
static const size_t O_ATT  = O_SAIN + 1843200;
static const size_t O_QPROJ= O_ATT  + 614400;
static const size_t O_PROJ = O_QPROJ+ 614400;
static const size_t O_TMP  = O_PROJ + 614400;
static const size_t O_FFNH = O_TMP  + 614400;
static const size_t O_QF   = O_FFNH + 2457600;
static const size_t O_H1   = O_QF   + 102400;
static const size_t O_QPOS = O_H1   + 102400;
static const size_t O_ACTF = O_QPOS + 1200;
static const size_t O_ACTN = O_ACTF + 2400;
static const size_t O_INV  = O_ACTN + 2400;
static const size_t O_PML  = O_INV  + 192;
static const size_t O_PACC = O_PML  + 307200;

// ---------------- output offsets (floats) ----------------
#define OO_QFEAT   0
#define OO_QPOS    102400
#define OO_POSBEV  103600
#define OO_CENTERS 104400
#define OO_HEIGHTS 106000

// ============ 4x4 inverse (adjugate; row-major in/out) ============
__global__ void inv4_kernel(const float* __restrict__ A, float* __restrict__ Ainv) {
    int t = blockIdx.x * blockDim.x + threadIdx.x;
    if (t >= BV_) return;
    const float* m = A + t*16;
    float i0  =  m[5]*m[10]*m[15] - m[5]*m[11]*m[14] - m[9]*m[6]*m[15] + m[9]*m[7]*m[14] + m[13]*m[6]*m[11] - m[13]*m[7]*m[10];
    float i4  = -m[4]*m[10]*m[15] + m[4]*m[11]*m[14] + m[8]*m[6]*m[15] - m[8]*m[7]*m[14] - m[12]*m[6]*m[11] + m[12]*m[7]*m[10];
    float i8  =  m[4]*m[9]*m[15]  - m[4]*m[11]*m[13] - m[8]*m[5]*m[15] + m[8]*m[7]*m[13] + m[12]*m[5]*m[11] - m[12]*m[7]*m[9];
    float i12 = -m[4]*m[9]*m[14]  + m[4]*m[10]*m[13] + m[8]*m[5]*m[14] - m[8]*m[6]*m[13] - m[12]*m[5]*m[10] + m[12]*m[6]*m[9];
    float i1  = -m[1]*m[10]*m[15] + m[1]*m[11]*m[14] + m[9]*m[2]*m[15] - m[9]*m[3]*m[14] - m[13]*m[2]*m[11] + m[13]*m[3]*m[10];
    float i5  =  m[0]*m[10]*m[15] - m[0]*m[11]*m[14] - m[8]*m[2]*m[15] + m[8]*m[3]*m[14] + m[12]*m[2]*m[11] - m[12]*m[3]*m[10];
    float i9  = -m[0]*m[9]*m[15]  + m[0]*m[11]*m[13] + m[8]*m[1]*m[15] - m[8]*m[3]*m[13] - m[12]*m[1]*m[11] + m[12]*m[3]*m[9];
    float i13 =  m[0]*m[9]*m[14]  - m[0]*m[10]*m[13] - m[8]*m[1]*m[14] + m[8]*m[2]*m[13] + m[12]*m[1]*m[10] - m[12]*m[2]*m[9];
    float i2  =  m[1]*m[6]*m[15]  - m[1]*m[7]*m[14]  - m[5]*m[2]*m[15] + m[5]*m[3]*m[14] + m[13]*m[2]*m[7]  - m[13]*m[3]*m[6];
    float i6  = -m[0]*m[6]*m[15]  + m[0]*m[7]*m[14]  + m[4]*m[2]*m[15] - m[4]*m[3]*m[14] - m[12]*m[2]*m[7]  + m[12]*m[3]*m[6];
    float i10 =  m[0]*m[5]*m[15]  - m[0]*m[7]*m[13]  - m[4]*m[1]*m[15] + m[4]*m[3]*m[13] + m[12]*m[1]*m[7]  - m[12]*m[3]*m[5];
    float i14 = -m[0]*m[5]*m[14]  + m[0]*m[6]*m[13]  + m[4]*m[1]*m[14] - m[4]*m[2]*m[13] - m[12]*m[1]*m[6]  + m[12]*m[2]*m[5];
    float i3  = -m[1]*m[6]*m[11]  + m[1]*m[7]*m[10]  + m[5]*m[2]*m[11] - m[5]*m[3]*m[10] - m[9]*m[2]*m[7]   + m[9]*m[3]*m[6];
    float i7  =  m[0]*m[6]*m[11]  - m[0]*m[7]*m[10]  - m[4]*m[2]*m[11] + m[4]*m[3]*m[10] + m[8]*m[2]*m[7]   - m[8]*m[3]*m[6];
    float i11 = -m[0]*m[5]*m[11]  + m[0]*m[7]*m[9]   + m[4]*m[1]*m[11] - m[4]*m[3]*m[9]  - m[8]*m[1]*m[7]   + m[8]*m[3]*m[5];
    float i15 =  m[0]*m[5]*m[10]  - m[0]*m[6]*m[9]   - m[4]*m[1]*m[10] + m[4]*m[2]*m[9]  + m[8]*m[1]*m[6]   - m[8]*m[2]*m[5];
    float det = m[0]*i0 + m[1]*i4 + m[2]*i8 + m[3]*i12;
    float r = 1.0f / det;
    float* o = Ainv + t*16;
    o[0]=i0*r;  o[1]=i1*r;  o[2]=i2*r;  o[3]=i3*r;
    o[4]=i4*r;  o[5]=i5*r;  o[6]=i6*r;  o[7]=i7*r;
    o[8]=i8*r;  o[9]=i9*r;  o[10]=i10*r;o[11]=i11*r;
    o[12]=i12*r;o[13]=i13*r;o[14]=i14*r;o[15]=i15*r;
}

// ============ cam features: (B,V,N,D*3) ============
__global__ void cam_kernel(const float* __restrict__ pos, const int* __restrict__ hw,
                           const float* __restrict__ inv, float* __restrict__ cam) {
    int g = blockIdx.x * blockDim.x + threadIdx.x;
    const int total = BV_ * N_ * D_;
    if (g >= total) return;
    int d  = g & 31;
    int n  = (g >> 5) % N_;
    int bv = g / (N_ * D_);
    int b  = bv / V_;
    float sx = pos[n*2+0], sy = pos[n*2+1];
    float mx = (float)hw[b*2+1], my = (float)hw[b*2+0];
    float px = mx / (1.0f + expf(-sx));
    float py = my / (1.0f + expf(-sy));
    const float binsz = 53.0f / 1056.0f;
    float cd = fmaxf(1.0f + binsz * (float)d * (float)(d+1), 1e-5f);
    float h0 = px*cd, h1 = py*cd, h2 = cd, h3 = 1.0f;
    const float* iv = inv + bv*16;
    float* o = cam + ((size_t)bv * N_ + n) * 96 + d*3;
    o[0] = iv[0]*h0 + iv[1]*h1 + iv[2]*h2  + iv[3]*h3;
    o[1] = iv[4]*h0 + iv[5]*h1 + iv[6]*h2  + iv[7]*h3;
    o[2] = iv[8]*h0 + iv[9]*h1 + iv[10]*h2 + iv[11]*h3;
}

// ============ keys transpose ============
__global__ void transpose_keys_kernel(const float* __restrict__ src, float* __restrict__ keys,
                                      int HW, int n_off) {
    __shared__ float tile[32][33];
    int bv = blockIdx.z;
    int x0 = blockIdx.x * 32;
    int c0 = blockIdx.y * 32;
    int tx = threadIdx.x, ty = threadIdx.y;
    tile[ty][tx] = src[((size_t)bv * C_ + c0 + ty) * HW + x0 + tx];
    __syncthreads();
    keys[((size_t)bv * N_ + n_off + x0 + ty) * C_ + c0 + tx] = tile[tx][ty];
}

// ============ active mask ============
__global__ void mask_kernel(const int* __restrict__ qvm, float* __restrict__ actF, float* __restrict__ actNeg) {
    int bv = blockIdx.x;
    int b = bv / V_, v = bv % V_;
    int p = threadIdx.x;
    int m = 0;
    if (p < P_) m = (qvm[(b*P_ + p)*V_ + v] > 0) ? 1 : 0;
    __shared__ int s[256];
    s[threadIdx.x] = m;
    __syncthreads();
    for (int off = 128; off > 0; off >>= 1) {
        if (threadIdx.x < off) s[threadIdx.x] += s[threadIdx.x + off];
        __syncthreads();
    }
    int valid = (s[0] > 1);
    if (p < P_) {
        int act = m && valid;
        actF[bv*P_ + p]   = act ? 1.0f : 0.0f;
        actNeg[bv*P_ + p] = act ? 0.0f : NEGV;
    }
}

// ============ small GEMM (kept for pe_q path, K=3 etc.) ============
template<int RELU, int FUSE>
__global__ __launch_bounds__(256) void gemm_kernel(
    const float* __restrict__ A, const float* __restrict__ A2,
    const float* __restrict__ W, const float* __restrict__ bias,
    float* __restrict__ Cmat, int M, int N, int K)
{
    __shared__ float As[16][68];
    __shared__ float Ws[16][68];
    int m0 = blockIdx.y * 64, n0 = blockIdx.x * 64;
    int tid = threadIdx.x;
    int tx = tid & 15, ty = tid >> 4;
    int ar = tid >> 2;
    int ac = (tid & 3) * 4;
    float acc[4][4] = {};
    for (int k0 = 0; k0 < K; k0 += 16) {
        #pragma unroll
        for (int j = 0; j < 4; ++j) {
            int kk = ac + j;
            int m = m0 + ar;
            float v = 0.0f;
            if (m < M && (k0 + kk) < K) {
                v = A[(size_t)m * K + k0 + kk];
                if (FUSE) v += A2[(size_t)m * K + k0 + kk];
            }
            As[kk][ar] = v;
        }
        #pragma unroll
        for (int j = 0; j < 4; ++j) {
            int kk = ac + j;
            int n = n0 + ar;
            float v = 0.0f;
            if (n < N && (k0 + kk) < K) v = W[(size_t)n * K + k0 + kk];
            Ws[kk][ar] = v;
        }
        __syncthreads();
        #pragma unroll
        for (int kk = 0; kk < 16; ++kk) {
            const float4 a = *(const float4*)&As[kk][ty*4];
            const float4 w = *(const float4*)&Ws[kk][tx*4];
            acc[0][0] = fmaf(a.x, w.x, acc[0][0]); acc[0][1] = fmaf(a.x, w.y, acc[0][1]);
            acc[0][2] = fmaf(a.x, w.z, acc[0][2]); acc[0][3] = fmaf(a.x, w.w, acc[0][3]);
            acc[1][0] = fmaf(a.y, w.x, acc[1][0]); acc[1][1] = fmaf(a.y, w.y, acc[1][1]);
            acc[1][2] = fmaf(a.y, w.z, acc[1][2]); acc[1][3] = fmaf(a.y, w.w, acc[1][3]);
            acc[2][0] = fmaf(a.z, w.x, acc[2][0]); acc[2][1] = fmaf(a.z, w.y, acc[2][1]);
            acc[2][2] = fmaf(a.z, w.z, acc[2][2]); acc[2][3] = fmaf(a.z, w.w, acc[2][3]);
            acc[3][0] = fmaf(a.w, w.x, acc[3][0]); acc[3][1] = fmaf(a.w, w.y, acc[3][1]);
            acc[3][2] = fmaf(a.w, w.z, acc[3][2]); acc[3][3] = fmaf(a.w, w.w, acc[3][3]);
        }
        __syncthreads();
    }
    #pragma unroll
    for (int i = 0; i < 4; ++i) {
        int m = m0 + ty*4 + i;
        if (m >= M) continue;
        #pragma unroll
        for (int j = 0; j < 4; ++j) {
            int n = n0 + tx*4 + j;
            if (n >= N) continue;
            float v = acc[i][j] + bias[n];
            if (RELU) v = fmaxf(v, 0.0f);
            Cmat[(size_t)m * N + n] = v;
        }
    }
}

// ============ big GEMM: 128x128 tile, 8x8 micro-tile ============
// C[M,N] = act(A(+A2) @ W^T + bias). A (M,K) rm, W (N,K) rm.
// blockIdx.x = M tiles (fastest -> column sweep reuses W panel),
// blockIdx.y = N tiles. Requires N%128==0, K%16==0; M guarded.
template<int RELU, int FUSE>
__global__ __launch_bounds__(256) void gemm128_kernel(
    const float* __restrict__ A, const float* __restrict__ A2,
    const float* __restrict__ W, const float* __restrict__ bias,
    float* __restrict__ Cmat, int M, int N, int K)
{
    __shared__ float As[16][132];
    __shared__ float Ws[16][132];
    const int tid = threadIdx.x;
    const int m0 = blockIdx.x * 128;
    const int n0 = blockIdx.y * 128;
    const int tx = tid & 15, ty = tid >> 4;

    // staging: thread loads rows (srow, srow+64), k-chunk skc..skc+3 of the 128x16 tiles
    const int srow = tid >> 2;            // 0..63
    const int skc  = (tid & 3) * 4;       // 0,4,8,12

    const int arow0 = min(m0 + srow,      M - 1);
    const int arow1 = min(m0 + srow + 64, M - 1);
    const float* Ab0 = A + (size_t)arow0 * K + skc;
    const float* Ab1 = A + (size_t)arow1 * K + skc;
    const float* A2b0 = FUSE ? (A2 + (size_t)arow0 * K + skc) : nullptr;
    const float* A2b1 = FUSE ? (A2 + (size_t)arow1 * K + skc) : nullptr;
    const float* Wb0 = W + (size_t)(n0 + srow) * K + skc;
    const float* Wb1 = W + (size_t)(n0 + srow + 64) * K + skc;

    float acc[8][8] = {};

    for (int k0 = 0; k0 < K; k0 += 16) {
        float4 a0 = *(const float4*)(Ab0 + k0);
        float4 a1 = *(const float4*)(Ab1 + k0);
        float4 w0 = *(const float4*)(Wb0 + k0);
        float4 w1 = *(const float4*)(Wb1 + k0);
        if (FUSE) {
            float4 e0 = *(const float4*)(A2b0 + k0);
            float4 e1 = *(const float4*)(A2b1 + k0);
            a0.x += e0.x; a0.y += e0.y; a0.z += e0.z; a0.w += e0.w;
            a1.x += e1.x; a1.y += e1.y; a1.z += e1.z; a1.w += e1.w;
        }
        __syncthreads();   // previous iteration's compute done reading LDS
        As[skc+0][srow] = a0.x; As[skc+1][srow] = a0.y; As[skc+2][srow] = a0.z; As[skc+3][srow] = a0.w;
        As[skc+0][srow+64] = a1.x; As[skc+1][srow+64] = a1.y; As[skc+2][srow+64] = a1.z; As[skc+3][srow+64] = a1.w;
        Ws[skc+0][srow] = w0.x; Ws[skc+1][srow] = w0.y; Ws[skc+2][srow] = w0.z; Ws[skc+3][srow] = w0.w;
        Ws[skc+0][srow+64] = w1.x; Ws[skc+1][srow+64] = w1.y; Ws[skc+2][srow+64] = w1.z; Ws[skc+3][srow+64] = w1.w;
        __syncthreads();
        #pragma unroll
        for (int kk = 0; kk < 16; ++kk) {
            float av[8], bv[8];
            *(float4*)&av[0] = *(const float4*)&As[kk][ty*8];
            *(float4*)&av[4] = *(const float4*)&As[kk][ty*8+4];
            *(float4*)&bv[0] = *(const float4*)&Ws[kk][tx*8];
            *(float4*)&bv[4] = *(const float4*)&Ws[kk][tx*8+4];
            #pragma unroll
            for (int i = 0; i < 8; ++i)
                #pragma unroll
                for (int j = 0; j < 8; ++j)
                    acc[i][j] = fmaf(av[i], bv[j], acc[i][j]);
        }
    }

    float bn[8];
    #pragma unroll
    for (int j = 0; j < 8; ++j) bn[j] = bias[n0 + tx*8 + j];

    #pragma unroll
    for (int i = 0; i < 8; ++i) {
        int m = m0 + ty*8 + i;
        if (m >= M) continue;
        float o[8];
        #pragma unroll
        for (int j = 0; j < 8; ++j) {
            float v = acc[i][j] + bn[j];
            if (RELU) v = fmaxf(v, 0.0f);
            o[j] = v;
        }
        float* cp = Cmat + (size_t)m * N + n0 + tx*8;
        *(float4*)cp       = *(float4*)&o[0];
        *(float4*)(cp + 4) = *(float4*)&o[4];
    }
}

// ============ LayerNorm over C=256 of (a+b), wave per row ============
__global__ __launch_bounds__(256) void ln_kernel(const float* __restrict__ Xa, const float* __restrict__ Xb,
    const float* __restrict__ g, const float* __restrict__ beta, float* __restrict__ out, int rows)
{
    int wid  = (blockIdx.x * blockDim.x + threadIdx.x) >> 6;
    int lane = threadIdx.x & 63;
    if (wid >= rows) return;
    float4 x = ((const float4*)(Xa + (size_t)wid * C_))[lane];
    float4 y = ((const float4*)(Xb + (size_t)wid * C_))[lane];
    x.x += y.x; x.y += y.y; x.z += y.z; x.w += y.w;
    float s = x.x + x.y + x.z + x.w;
    for (int d = 32; d > 0; d >>= 1) s += __shfl_xor(s, d);
    float mean = s * (1.0f / C_);
    float dx = x.x - mean, dy = x.y - mean, dz = x.z - mean, dw = x.w - mean;
    float v = dx*dx + dy*dy + dz*dz + dw*dw;
    for (int d = 32; d > 0; d >>= 1) v += __shfl_xor(v, d);
    float rstd = 1.0f / sqrtf(v * (1.0f / C_) + 1e-5f);
    float4 gg = ((const float4*)g)[lane];
    float4 bb = ((const float4*)beta)[lane];
    float4 o;
    o.x = dx * rstd * gg.x + bb.x;
    o.y = dy * rstd * gg.y + bb.y;
    o.z = dz * rstd * gg.z + bb.z;
    o.w = dw * rstd * gg.w + bb.w;
    ((float4*)(out + (size_t)wid * C_))[lane] = o;
}

// ============ x broadcast ============
__global__ void xbcast_kernel(const float* __restrict__ qf, float* __restrict__ x) {
    __shared__ float tile[32][33];
    int b  = blockIdx.z;
    int p0 = blockIdx.x * 32, c0 = blockIdx.y * 32;
    int tx = threadIdx.x, ty = threadIdx.y;
    float v = 0.0f;
    if (p0 + tx < P_) v = qf[((size_t)b * C_ + c0 + ty) * P_ + p0 + tx];
    tile[ty][tx] = v;
    __syncthreads();
    int p = p0 + ty;
    if (p < P_) {
        float val = tile[tx][ty];
        #pragma unroll
        for (int vv = 0; vv < V_; ++vv)
            x[(((size_t)(b*V_ + vv) * P_) + p) * C_ + c0 + tx] = val;
    }
}

// ============ out = x + broadcast_over_V(peq) ============
__global__ void bcast_add_kernel(const float* __restrict__ x, const float* __restrict__ peq, float* __restrict__ out) {
    int g = blockIdx.x * blockDim.x + threadIdx.x;
    const int total = ROWS_ * C_ / 4;
    if (g >= total) return;
    int c4 = g & 63;
    int rest = g >> 6;
    int p  = rest % P_;
    int bv = rest / P_;
    int b  = bv / V_;
    float4 xv = ((const float4*)x)[g];
    float4 pv = ((const float4*)peq)[((size_t)(b*P_ + p)) * 64 + c4];
    float4 o; o.x = xv.x + pv.x; o.y = xv.y + pv.y; o.z = xv.z + pv.z; o.w = xv.w + pv.w;
    ((float4*)out)[g] = o;
}

// ============ attention ============
__global__ __launch_bounds__(256) void attn_kernel(
    const float* __restrict__ Q, int qstride,
    const float* __restrict__ Kp, int kstride,
    const float* __restrict__ Vp, int vstride,
    const float* __restrict__ biasNeg,
    float* __restrict__ pAcc, float* __restrict__ pML,
    int NK, int S, float scale)
{
    int split = blockIdx.x, bvh = blockIdx.y;
    int bv = bvh >> 3, h = bvh & 7;
    int p = threadIdx.x;
    bool act = p < P_;
    int per = (NK + S - 1) / S;
    int k0 = split * per;
    int k1 = min(NK, k0 + per);

    __shared__ float Ks[32][36];
    __shared__ float Vs[32][36];
    __shared__ float Bs[32];

    float q[32];
    const float* qrow = Q + ((size_t)bv * P_ + (act ? p : 0)) * qstride + h * 32;
    #pragma unroll
    for (int j = 0; j < 32; j += 4) {
        float4 t = *(const float4*)(qrow + j);
        q[j] = t.x; q[j+1] = t.y; q[j+2] = t.z; q[j+3] = t.w;
    }
    float m = -INFINITY, l = 0.0f;
    float acc[32] = {};

    for (int kt = k0; kt < k1; kt += 32) {
        int kmax = min(32, k1 - kt);
        __syncthreads();
        {
            int t = threadIdx.x;
            int key = t >> 3, f = (t & 7) << 2;
            if (key < kmax) {
                const float* kr = Kp + ((size_t)bv * NK + kt + key) * kstride + h*32 + f;
                *(float4*)&Ks[key][f] = *(const float4*)kr;
                const float* vr = Vp + ((size_t)bv * NK + kt + key) * vstride + h*32 + f;
                *(float4*)&Vs[key][f] = *(const float4*)vr;
            }
            if (t < kmax) Bs[t] = biasNeg ? biasNeg[bv * P_ + kt + t] : 0.0f;
        }
        __syncthreads();
        if (act) {
            for (int k = 0; k < kmax; ++k) {
                const float4* k4 = (const float4*)&Ks[k][0];
                float s0 = 0, s1 = 0, s2 = 0, s3 = 0;
                #pragma unroll
                for (int jj = 0; jj < 8; ++jj) {
                    float4 kv = k4[jj];
                    s0 = fmaf(q[4*jj+0], kv.x, s0);
                    s1 = fmaf(q[4*jj+1], kv.y, s1);
                    s2 = fmaf(q[4*jj+2], kv.z, s2);
                    s3 = fmaf(q[4*jj+3], kv.w, s3);
                }
                float s = ((s0 + s1) + (s2 + s3)) * scale + Bs[k];
                const float4* v4 = (const float4*)&Vs[k][0];
                if (__any(s > m)) {
                    float mn = fmaxf(m, s);
                    float corr = __expf(m - mn);
                    float pr = __expf(s - mn);
                    m = mn;
                    l = fmaf(l, corr, pr);
                    #pragma unroll
                    for (int jj = 0; jj < 8; ++jj) {
                        float4 vv = v4[jj];
                        acc[4*jj+0] = fmaf(acc[4*jj+0], corr, pr * vv.x);
                        acc[4*jj+1] = fmaf(acc[4*jj+1], corr, pr * vv.y);
                        acc[4*jj+2] = fmaf(acc[4*jj+2], corr, pr * vv.z);
                        acc[4*jj+3] = fmaf(acc[4*jj+3], corr, pr * vv.w);
                    }
                } else {
                    float pr = __expf(s - m);
                    l += pr;
                    #pragma unroll
                    for (int jj = 0; jj < 8; ++jj) {
                        float4 vv = v4[jj];
                        acc[4*jj+0] = fmaf(pr, vv.x, acc[4*jj+0]);
                        acc[4*jj+1] = fmaf(pr, vv.y, acc[4*jj+1]);
                        acc[4*jj+2] = fmaf(pr, vv.z, acc[4*jj+2]);
                        acc[4*jj+3] = fmaf(pr, vv.w, acc[4*jj+3]);
                    }
                }
            }
        }
    }
    if (act) {
        size_t base = ((size_t)bvh * S + split) * 32 * P_ + p;
        #pragma unroll
        for (int j = 0; j < 32; ++j) pAcc[base + (size_t)j * P_] = acc[j];
        size_t mb = ((size_t)bvh * S + split) * 2 * P_ + p;
        pML[mb] = m; pML[mb + P_] = l;
    }
}

// ============ combine split partials ============
template<int S>
__global__ void attn_combine_kernel(const float* __restrict__ pAcc, const float* __restrict__ pML,
                                    float* __restrict__ Out)
{
    int g = blockIdx.x * blockDim.x + threadIdx.x;
    if (g >= BVH_ * P_) return;
    int p = g % P_;
    int bvh = g / P_;
    int bv = bvh >> 3, h = bvh & 7;
    float mg = -INFINITY;
    #pragma unroll
    for (int s = 0; s < S; ++s) mg = fmaxf(mg, pML[((size_t)bvh * S + s) * 2 * P_ + p]);
    float w[S];
    float L = 0.0f;
    #pragma unroll
    for (int s = 0; s < S; ++s) {
        float ms = pML[((size_t)bvh * S + s) * 2 * P_ + p];
        float ls = pML[((size_t)bvh * S + s) * 2 * P_ + P_ + p];
        float ws = __expf(ms - mg);
        w[s] = ws;
        L = fmaf(ls, ws, L);
    }
    float invL = 1.0f / L;
    float* orow = Out + ((size_t)bv * P_ + p) * C_ + h * 32;
    #pragma unroll
    for (int j = 0; j < 32; ++j) {
        float acc = 0.0f;
        #pragma unroll
        for (int s = 0; s < S; ++s)
            acc = fmaf(pAcc[(((size_t)bvh * S + s) * 32 + j) * P_ + p], w[s], acc);
        orow[j] = acc * invL;
    }
}

// ============ aggregation over views ============
__global__ void agg_kernel(const float* __restrict__ x, const float* __restrict__ actF,
                           float* __restrict__ qf, float* __restrict__ qf_out) {
    int bp = blockIdx.x;
    int b = bp / P_, p = bp % P_;
    int c = threadIdx.x;
    float sum = 0.0f, cnt = 0.0f;
    #pragma unroll
    for (int v = 0; v < V_; ++v) {
        float a = actF[(b*V_ + v) * P_ + p];
        cnt += a;
        sum = fmaf(a, x[(((size_t)(b*V_ + v)) * P_ + p) * C_ + c], sum);
    }
    float r = sum / (cnt + 1e-4f);
    qf[((size_t)b * C_ + c) * P_ + p] = r;
    if (qf_out) qf_out[((size_t)b * C_ + c) * P_ + p] = r;
}

// ============ head layer 1 ============
__global__ void head1_kernel(const float* __restrict__ w1, const float* __restrict__ b1,
                             const float* __restrict__ qf, float* __restrict__ h1out) {
    int g = blockIdx.x * blockDim.x + threadIdx.x;
    if (g >= B_ * C_ * P_) return;
    int p = g % P_;
    int o = (g / P_) % C_;
    int b = g / (P_ * C_);
    float s = b1[o];
    const float* wr = w1 + (size_t)o * C_;
    const float* qc = qf + (size_t)b * C_ * P_ + p;
    for (int c = 0; c < C_; ++c) s = fmaf(wr[c], qc[(size_t)c * P_], s);
    h1out[g] = fmaxf(s, 0.0f);
}

// ============ head layer 2 + outputs ============
__global__ void center_kernel(const float* __restrict__ w2, const float* __restrict__ b2,
                              const float* __restrict__ h1, const float* __restrict__ qpos_in,
                              float* __restrict__ qpos_ws, float* __restrict__ out, int layer) {
    int g = blockIdx.x * blockDim.x + threadIdx.x;
    if (g >= B_ * P_) return;
    int p = g % P_, b = g / P_;
    float c0 = b2[0], c1 = b2[1], c2 = b2[2];
    const float* hc = h1 + (size_t)b * C_ * P_ + p;
    for (int c = 0; c < C_; ++c) {
        float hv = hc[(size_t)c * P_];
        c0 = fmaf(w2[c], hv, c0);
        c1 = fmaf(w2[C_ + c], hv, c1);
        c2 = fmaf(w2[2*C_ + c], hv, c2);
    }
    const float* qp = qpos_in + ((size_t)b * P_ + p) * 3;
    c0 += qp[0]; c1 += qp[1]; c2 += qp[2];
    float* qw = qpos_ws + ((size_t)b * P_ + p) * 3;
    qw[0] = c0; qw[1] = c1; qw[2] = c2;
    float cx = (c0 + 54.0f) / 108.0f * 180.0f;
    float cy = (c1 + 54.0f) / 108.0f * 180.0f;
    float* centers = out + OO_CENTERS + ((size_t)(layer * B_ + b) * 2) * P_;
    centers[p] = cx;
    centers[P_ + p] = cy;
    out[OO_HEIGHTS + (size_t)(layer * B_ + b) * P_ + p] = c2;
    if (layer == L_ - 1) {
        float* qo = out + OO_QPOS + ((size_t)b * P_ + p) * 3;
        qo[0] = c0; qo[1] = c1; qo[2] = c2;
        float* pb = out + OO_POSBEV + ((size_t)b * P_ + p) * 2;
        pb[0] = cx; pb[1] = cy;
    }
}

// =====================================================================
extern "C" void kernel_launch(void* const* d_in, const int* in_sizes, int n_in,
                              void* d_out, int out_size, void* d_ws, size_t ws_size,
                              hipStream_t stream) {
    const float* in_qfeat = (const float*)d_in[0];
    const float* in_qpos  = (const float*)d_in[1];
    const int*   in_qvm   = (const int*)d_in[2];
    const float* in_f0    = (const float*)d_in[3];
    const float* in_f1    = (const float*)d_in[4];
    const float* in_pos   = (const float*)d_in[5];
    const float* in_l2i   = (const float*)d_in[6];
    const int*   in_hw    = (const int*)d_in[7];
    const float* qpos_w1  = (const float*)d_in[8];
    const float* qpos_b1  = (const float*)d_in[9];
    const float* qpos_w2  = (const float*)d_in[10];
    const float* qpos_b2  = (const float*)d_in[11];
    const float* kpos_w1  = (const float*)d_in[12];
    const float* kpos_b1  = (const float*)d_in[13];
    const float* kpos_w2  = (const float*)d_in[14];
    const float* kpos_b2  = (const float*)d_in[15];
    const float* sa_in_w  = (const float*)d_in[16];
    const float* sa_in_b  = (const float*)d_in[17];
    const float* sa_out_w = (const float*)d_in[18];
    const float* sa_out_b = (const float*)d_in[19];
    const float* ca_in_w  = (const float*)d_in[20];
    const float* ca_in_b  = (const float*)d_in[21];
    const float* ca_out_w = (const float*)d_in[22];
    const float* ca_out_b = (const float*)d_in[23];
    const float* ffn_w1   = (const float*)d_in[24];
    const float* ffn_b1   = (const float*)d_in[25];
    const float* ffn_w2   = (const float*)d_in[26];
    const float* ffn_b2   = (const float*)d_in[27];
    const float* n1_g     = (const float*)d_in[28];
    const float* n1_b     = (const float*)d_in[29];
    const float* n2_g     = (const float*)d_in[30];
    const float* n2_b     = (const float*)d_in[31];
    const float* n3_g     = (const float*)d_in[32];
    const float* n3_b     = (const float*)d_in[33];
    const float* head_w1  = (const float*)d_in[34];
    const float* head_b1  = (const float*)d_in[35];
    const float* head_w2  = (const float*)d_in[36];
    const float* head_b2  = (const float*)d_in[37];

    float* ws   = (float*)d_ws;
    float* KEYS = ws + O_KEYS;
    float* CAM  = ws + O_CAM;
    float* PEK  = ws + O_PEK;
    float* HID  = ws + O_HID;
    float* KVP  = ws + O_KVP;
    float* PEQH = ws + O_PEQH;
    float* PEQ  = ws + O_PEQ;
    float* X    = ws + O_X;
    float* QKV  = ws + O_QKV;
    float* SAIN = ws + O_SAIN;
    float* ATT  = ws + O_ATT;
    float* QPROJ= ws + O_QPROJ;
    float* PROJ = ws + O_PROJ;
    float* TMP  = ws + O_TMP;
    float* FFNH = ws + O_FFNH;
    float* QF   = ws + O_QF;
    float* H1   = ws + O_H1;
    float* QPOS = ws + O_QPOS;
    float* ACTF = ws + O_ACTF;
    float* ACTN = ws + O_ACTN;
    float* INV  = ws + O_INV;
    float* PML  = ws + O_PML;
    float* PACC = ws + O_PACC;
    float* OUT  = (float*)d_out;

    const float scale = 0.17677669529663687f;   // 1/sqrt(32)

    // ---- one-time precompute ----
    inv4_kernel<<<1, 64, 0, stream>>>(in_l2i, INV);
    cam_kernel<<<(BV_*N_*D_ + 255)/256, 256, 0, stream>>>(in_pos, in_hw, INV, CAM);
    transpose_keys_kernel<<<dim3(HW0T/32, C_/32, BV_), dim3(32,32), 0, stream>>>(in_f0, KEYS, HW0T, 0);
    transpose_keys_kernel<<<dim3(HW1T/32, C_/32, BV_), dim3(32,32), 0, stream>>>(in_f1, KEYS, HW1T, HW0T);
    mask_kernel<<<BV_, 256, 0, stream>>>(in_qvm, ACTF, ACTN);

    const int MT_NK = NKTOT / 128;        // 330
    const int MT_R  = (ROWS_ + 127) / 128; // 19

    for (int l = 0; l < L_; ++l) {
        const float* qf_src   = (l == 0) ? in_qfeat : QF;
        const float* qpos_src = (l == 0) ? in_qpos  : QPOS;

        // pe_q MLP (400 rows): 3 -> 256 relu -> 256 (small kernel)
        gemm_kernel<1,0><<<dim3(4,7), 256, 0, stream>>>(qpos_src, nullptr, qpos_w1 + l*C_*3, qpos_b1 + l*C_, PEQH, 400, C_, 3);
        gemm_kernel<0,0><<<dim3(4,7), 256, 0, stream>>>(PEQH, nullptr, qpos_w2 + l*C_*C_, qpos_b2 + l*C_, PEQ, 400, C_, C_);

        // pe_k MLP (42240 rows): 96 -> 256 relu -> 256
        gemm128_kernel<1,0><<<dim3(MT_NK, 2), 256, 0, stream>>>(CAM, nullptr, kpos_w1 + l*C_*96, kpos_b1 + l*C_, HID, NKTOT, C_, 96);
        gemm128_kernel<0,0><<<dim3(MT_NK, 2), 256, 0, stream>>>(HID, nullptr, kpos_w2 + l*C_*C_, kpos_b2 + l*C_, PEK, NKTOT, C_, C_);

        // x = broadcast(q_feat); qkv = x + pe_q
        xbcast_kernel<<<dim3(7, 8, B_), dim3(32,32), 0, stream>>>(qf_src, X);
        bcast_add_kernel<<<600, 256, 0, stream>>>(X, PEQ, QKV);

        // --- self attention ---
        gemm128_kernel<0,0><<<dim3(MT_R, 6), 256, 0, stream>>>(QKV, nullptr, sa_in_w + l*768*C_, sa_in_b + l*768, SAIN, ROWS_, 768, C_);
        attn_kernel<<<dim3(4, BVH_), 256, 0, stream>>>(SAIN, 768, SAIN + 256, 768, SAIN + 512, 768, ACTN, PACC, PML, P_, 4, scale);
        attn_combine_kernel<4><<<(BVH_*P_)/256, 256, 0, stream>>>(PACC, PML, ATT);
        gemm128_kernel<0,0><<<dim3(MT_R, 2), 256, 0, stream>>>(ATT, nullptr, sa_out_w + l*C_*C_, sa_out_b + l*C_, PROJ, ROWS_, C_, C_);
        ln_kernel<<<600, 256, 0, stream>>>(X, PROJ, n1_g + l*C_, n1_b + l*C_, X, ROWS_);

        // --- cross attention ---
        bcast_add_kernel<<<600, 256, 0, stream>>>(X, PEQ, TMP);
        gemm128_kernel<0,0><<<dim3(MT_R, 2), 256, 0, stream>>>(TMP, nullptr, ca_in_w + l*768*C_, ca_in_b + l*768, QPROJ, ROWS_, C_, C_);
        gemm128_kernel<0,1><<<dim3(MT_NK, 4), 256, 0, stream>>>(KEYS, PEK, ca_in_w + l*768*C_ + C_*C_, ca_in_b + l*768 + C_, KVP, NKTOT, 512, C_);
        attn_kernel<<<dim3(8, BVH_), 256, 0, stream>>>(QPROJ, 256, KVP, 512, KVP + 256, 512, nullptr, PACC, PML, N_, 8, scale);
        attn_combine_kernel<8><<<(BVH_*P_)/256, 256, 0, stream>>>(PACC, PML, ATT);
        gemm128_kernel<0,0><<<dim3(MT_R, 2), 256, 0, stream>>>(ATT, nullptr, ca_out_w + l*C_*C_, ca_out_b + l*C_, PROJ, ROWS_, C_, C_);
        ln_kernel<<<600, 256, 0, stream>>>(X, PROJ, n2_g + l*C_, n2_b + l*C_, X, ROWS_);

        // --- FFN ---
        gemm128_kernel<1,0><<<dim3(MT_R, 8), 256, 0, stream>>>(X, nullptr, ffn_w1 + l*F_*C_, ffn_b1 + l*F_, FFNH, ROWS_, F_, C_);
        gemm128_kernel<0,0><<<dim3(MT_R, 2), 256, 0, stream>>>(FFNH, nullptr, ffn_w2 + l*C_*F_, ffn_b2 + l*C_, PROJ, ROWS_, C_, F_);
        ln_kernel<<<600, 256, 0, stream>>>(X, PROJ, n3_g + l*C_, n3_b + l*C_, X, ROWS_);

        // --- aggregate over views ---
        agg_kernel<<<B_*P_, 256, 0, stream>>>(X, ACTF, QF, (l == L_-1) ? (OUT + OO_QFEAT) : nullptr);

        // --- head ---
        head1_kernel<<<(B_*C_*P_ + 255)/256, 256, 0, stream>>>(head_w1, head_b1, QF, H1);
        center_kernel<<<(B_*P_ + 255)/256, 256, 0, stream>>>(head_w2, head_b2, H1, qpos_src, QPOS, OUT, l);
    }
}

// Round 10
// 1930.558 us; speedup vs baseline: 1.5968x; 1.0641x over previous
//
#include <hip/hip_runtime.h>
#include <math.h>

#define B_ 2
#define V_ 6
#define C_ 256
#define P_ 200
#define H_ 8
#define D_ 32
#define L_ 2
#define F_ 1024
#define N_ 3520
#define HW0T 2816
#define HW1T 704
#define BV_ (B_*V_)
#define NKTOT (BV_*N_)
#define ROWS_ (BV_*P_)
#define BVH_ (BV_*H_)
#define NEGV -1000000000.0f

// ---------------- workspace offsets (in floats) ----------------
static const size_t O_KEYS = 0;
static const size_t O_CAM  = O_KEYS + (size_t)NKTOT*C_;
static const size_t O_PEK  = O_CAM  + (size_t)NKTOT*96;
static const size_t O_BIG  = O_PEK  + (size_t)NKTOT*C_;   // HID / KVP overlap
static const size_t O_HID  = O_BIG;
static const size_t O_KVP  = O_BIG;
static const size_t O_PEQH = O_BIG + (size_t)NKTOT*512;
static const size_t O_PEQ  = O_PEQH + 102400;
static const size_t O_X    = O_PEQ  + 102400;
static const size_t O_QKV  = O_X    + 614400;
static const size_t O_SAIN = O_QKV  + 614400;
static const size_t O_ATT  = O_SAIN + 1843200;
static const size_t O_QPROJ= O_ATT  + 614400;
static const size_t O_PROJ = O_QPROJ+ 614400;
static const size_t O_TMP  = O_PROJ + 614400;
static const size_t O_FFNH = O_TMP  + 614400;
static const size_t O_QF   = O_FFNH + 2457600;
static const size_t O_QFT  = O_QF   + 102400;   // transposed q_feat (B,P,C) for head
static const size_t O_QPOS = O_QFT  + 102400;
static const size_t O_ACTF = O_QPOS + 1200;
static const size_t O_ACTN = O_ACTF + 2400;
static const size_t O_INV  = O_ACTN + 2400;
static const size_t O_PML  = O_INV  + 192;
static const size_t O_PACC = O_PML  + 307200;
// end = O_PACC + 4915200 floats (~244 MB)

// ---------------- output offsets (floats) ----------------
#define OO_QFEAT   0
#define OO_QPOS    102400
#define OO_POSBEV  103600
#define OO_CENTERS 104400
#define OO_HEIGHTS 106000

// ============ 4x4 inverse (adjugate; row-major in/out) ============
__global__ void inv4_kernel(const float* __restrict__ A, float* __restrict__ Ainv) {
    int t = blockIdx.x * blockDim.x + threadIdx.x;
    if (t >= BV_) return;
    const float* m = A + t*16;
    float i0  =  m[5]*m[10]*m[15] - m[5]*m[11]*m[14] - m[9]*m[6]*m[15] + m[9]*m[7]*m[14] + m[13]*m[6]*m[11] - m[13]*m[7]*m[10];
    float i4  = -m[4]*m[10]*m[15] + m[4]*m[11]*m[14] + m[8]*m[6]*m[15] - m[8]*m[7]*m[14] - m[12]*m[6]*m[11] + m[12]*m[7]*m[10];
    float i8  =  m[4]*m[9]*m[15]  - m[4]*m[11]*m[13] - m[8]*m[5]*m[15] + m[8]*m[7]*m[13] + m[12]*m[5]*m[11] - m[12]*m[7]*m[9];
    float i12 = -m[4]*m[9]*m[14]  + m[4]*m[10]*m[13] + m[8]*m[5]*m[14] - m[8]*m[6]*m[13] - m[12]*m[5]*m[10] + m[12]*m[6]*m[9];
    float i1  = -m[1]*m[10]*m[15] + m[1]*m[11]*m[14] + m[9]*m[2]*m[15] - m[9]*m[3]*m[14] - m[13]*m[2]*m[11] + m[13]*m[3]*m[10];
    float i5  =  m[0]*m[10]*m[15] - m[0]*m[11]*m[14] - m[8]*m[2]*m[15] + m[8]*m[3]*m[14] + m[12]*m[2]*m[11] - m[12]*m[3]*m[10];
    float i9  = -m[0]*m[9]*m[15]  + m[0]*m[11]*m[13] + m[8]*m[1]*m[15] - m[8]*m[3]*m[13] - m[12]*m[1]*m[11] + m[12]*m[3]*m[9];
    float i13 =  m[0]*m[9]*m[14]  - m[0]*m[10]*m[13] - m[8]*m[1]*m[14] + m[8]*m[2]*m[13] + m[12]*m[1]*m[10] - m[12]*m[2]*m[9];
    float i2  =  m[1]*m[6]*m[15]  - m[1]*m[7]*m[14]  - m[5]*m[2]*m[15] + m[5]*m[3]*m[14] + m[13]*m[2]*m[7]  - m[13]*m[3]*m[6];
    float i6  = -m[0]*m[6]*m[15]  + m[0]*m[7]*m[14]  + m[4]*m[2]*m[15] - m[4]*m[3]*m[14] - m[12]*m[2]*m[7]  + m[12]*m[3]*m[6];
    float i10 =  m[0]*m[5]*m[15]  - m[0]*m[7]*m[13]  - m[4]*m[1]*m[15] + m[4]*m[3]*m[13] + m[12]*m[1]*m[7]  - m[12]*m[3]*m[5];
    float i14 = -m[0]*m[5]*m[14]  + m[0]*m[6]*m[13]  + m[4]*m[1]*m[14] - m[4]*m[2]*m[13] - m[12]*m[1]*m[6]  + m[12]*m[2]*m[5];
    float i3  = -m[1]*m[6]*m[11]  + m[1]*m[7]*m[10]  + m[5]*m[2]*m[11] - m[5]*m[3]*m[10] - m[9]*m[2]*m[7]   + m[9]*m[3]*m[6];
    float i7  =  m[0]*m[6]*m[11]  - m[0]*m[7]*m[10]  - m[4]*m[2]*m[11] + m[4]*m[3]*m[10] + m[8]*m[2]*m[7]   - m[8]*m[3]*m[6];
    float i11 = -m[0]*m[5]*m[11]  + m[0]*m[7]*m[9]   + m[4]*m[1]*m[11] - m[4]*m[3]*m[9]  - m[8]*m[1]*m[7]   + m[8]*m[3]*m[5];
    float i15 =  m[0]*m[5]*m[10]  - m[0]*m[6]*m[9]   - m[4]*m[1]*m[10] + m[4]*m[2]*m[9]  + m[8]*m[1]*m[6]   - m[8]*m[2]*m[5];
    float det = m[0]*i0 + m[1]*i4 + m[2]*i8 + m[3]*i12;
    float r = 1.0f / det;
    float* o = Ainv + t*16;
    o[0]=i0*r;  o[1]=i1*r;  o[2]=i2*r;  o[3]=i3*r;
    o[4]=i4*r;  o[5]=i5*r;  o[6]=i6*r;  o[7]=i7*r;
    o[8]=i8*r;  o[9]=i9*r;  o[10]=i10*r;o[11]=i11*r;
    o[12]=i12*r;o[13]=i13*r;o[14]=i14*r;o[15]=i15*r;
}

// ============ cam features ============
__global__ void cam_kernel(const float* __restrict__ pos, const int* __restrict__ hw,
                           const float* __restrict__ inv, float* __restrict__ cam) {
    int g = blockIdx.x * blockDim.x + threadIdx.x;
    const int total = BV_ * N_ * D_;
    if (g >= total) return;
    int d  = g & 31;
    int n  = (g >> 5) % N_;
    int bv = g / (N_ * D_);
    int b  = bv / V_;
    float sx = pos[n*2+0], sy = pos[n*2+1];
    float mx = (float)hw[b*2+1], my = (float)hw[b*2+0];
    float px = mx / (1.0f + expf(-sx));
    float py = my / (1.0f + expf(-sy));
    const float binsz = 53.0f / 1056.0f;
    float cd = fmaxf(1.0f + binsz * (float)d * (float)(d+1), 1e-5f);
    float h0 = px*cd, h1 = py*cd, h2 = cd, h3 = 1.0f;
    const float* iv = inv + bv*16;
    float* o = cam + ((size_t)bv * N_ + n) * 96 + d*3;
    o[0] = iv[0]*h0 + iv[1]*h1 + iv[2]*h2  + iv[3]*h3;
    o[1] = iv[4]*h0 + iv[5]*h1 + iv[6]*h2  + iv[7]*h3;
    o[2] = iv[8]*h0 + iv[9]*h1 + iv[10]*h2 + iv[11]*h3;
}

// ============ keys transpose ============
__global__ void transpose_keys_kernel(const float* __restrict__ src, float* __restrict__ keys,
                                      int HW, int n_off) {
    __shared__ float tile[32][33];
    int bv = blockIdx.z;
    int x0 = blockIdx.x * 32;
    int c0 = blockIdx.y * 32;
    int tx = threadIdx.x, ty = threadIdx.y;
    tile[ty][tx] = src[((size_t)bv * C_ + c0 + ty) * HW + x0 + tx];
    __syncthreads();
    keys[((size_t)bv * N_ + n_off + x0 + ty) * C_ + c0 + tx] = tile[tx][ty];
}

// ============ active mask ============
__global__ void mask_kernel(const int* __restrict__ qvm, float* __restrict__ actF, float* __restrict__ actNeg) {
    int bv = blockIdx.x;
    int b = bv / V_, v = bv % V_;
    int p = threadIdx.x;
    int m = 0;
    if (p < P_) m = (qvm[(b*P_ + p)*V_ + v] > 0) ? 1 : 0;
    __shared__ int s[256];
    s[threadIdx.x] = m;
    __syncthreads();
    for (int off = 128; off > 0; off >>= 1) {
        if (threadIdx.x < off) s[threadIdx.x] += s[threadIdx.x + off];
        __syncthreads();
    }
    int valid = (s[0] > 1);
    if (p < P_) {
        int act = m && valid;
        actF[bv*P_ + p]   = act ? 1.0f : 0.0f;
        actNeg[bv*P_ + p] = act ? 0.0f : NEGV;
    }
}

// ============ small GEMM (pe_q path) ============
template<int RELU, int FUSE>
__global__ __launch_bounds__(256) void gemm_kernel(
    const float* __restrict__ A, const float* __restrict__ A2,
    const float* __restrict__ W, const float* __restrict__ bias,
    float* __restrict__ Cmat, int M, int N, int K)
{
    __shared__ float As[16][68];
    __shared__ float Ws[16][68];
    int m0 = blockIdx.y * 64, n0 = blockIdx.x * 64;
    int tid = threadIdx.x;
    int tx = tid & 15, ty = tid >> 4;
    int ar = tid >> 2;
    int ac = (tid & 3) * 4;
    float acc[4][4] = {};
    for (int k0 = 0; k0 < K; k0 += 16) {
        #pragma unroll
        for (int j = 0; j < 4; ++j) {
            int kk = ac + j;
            int m = m0 + ar;
            float v = 0.0f;
            if (m < M && (k0 + kk) < K) {
                v = A[(size_t)m * K + k0 + kk];
                if (FUSE) v += A2[(size_t)m * K + k0 + kk];
            }
            As[kk][ar] = v;
        }
        #pragma unroll
        for (int j = 0; j < 4; ++j) {
            int kk = ac + j;
            int n = n0 + ar;
            float v = 0.0f;
            if (n < N && (k0 + kk) < K) v = W[(size_t)n * K + k0 + kk];
            Ws[kk][ar] = v;
        }
        __syncthreads();
        #pragma unroll
        for (int kk = 0; kk < 16; ++kk) {
            const float4 a = *(const float4*)&As[kk][ty*4];
            const float4 w = *(const float4*)&Ws[kk][tx*4];
            acc[0][0] = fmaf(a.x, w.x, acc[0][0]); acc[0][1] = fmaf(a.x, w.y, acc[0][1]);
            acc[0][2] = fmaf(a.x, w.z, acc[0][2]); acc[0][3] = fmaf(a.x, w.w, acc[0][3]);
            acc[1][0] = fmaf(a.y, w.x, acc[1][0]); acc[1][1] = fmaf(a.y, w.y, acc[1][1]);
            acc[1][2] = fmaf(a.y, w.z, acc[1][2]); acc[1][3] = fmaf(a.y, w.w, acc[1][3]);
            acc[2][0] = fmaf(a.z, w.x, acc[2][0]); acc[2][1] = fmaf(a.z, w.y, acc[2][1]);
            acc[2][2] = fmaf(a.z, w.z, acc[2][2]); acc[2][3] = fmaf(a.z, w.w, acc[2][3]);
            acc[3][0] = fmaf(a.w, w.x, acc[3][0]); acc[3][1] = fmaf(a.w, w.y, acc[3][1]);
            acc[3][2] = fmaf(a.w, w.z, acc[3][2]); acc[3][3] = fmaf(a.w, w.w, acc[3][3]);
        }
        __syncthreads();
    }
    #pragma unroll
    for (int i = 0; i < 4; ++i) {
        int m = m0 + ty*4 + i;
        if (m >= M) continue;
        #pragma unroll
        for (int j = 0; j < 4; ++j) {
            int n = n0 + tx*4 + j;
            if (n >= N) continue;
            float v = acc[i][j] + bias[n];
            if (RELU) v = fmaxf(v, 0.0f);
            Cmat[(size_t)m * N + n] = v;
        }
    }
}

// ============ big GEMM: 128x128 tile, 8x8 micro (NKTOT gemms) ============
template<int RELU, int FUSE>
__global__ __launch_bounds__(256) void gemm128_kernel(
    const float* __restrict__ A, const float* __restrict__ A2,
    const float* __restrict__ W, const float* __restrict__ bias,
    float* __restrict__ Cmat, int M, int N, int K)
{
    __shared__ float As[16][132];
    __shared__ float Ws[16][132];
    const int tid = threadIdx.x;
    const int m0 = blockIdx.x * 128;
    const int n0 = blockIdx.y * 128;
    const int tx = tid & 15, ty = tid >> 4;
    const int srow = tid >> 2;
    const int skc  = (tid & 3) * 4;

    const int arow0 = min(m0 + srow,      M - 1);
    const int arow1 = min(m0 + srow + 64, M - 1);
    const float* Ab0 = A + (size_t)arow0 * K + skc;
    const float* Ab1 = A + (size_t)arow1 * K + skc;
    const float* A2b0 = FUSE ? (A2 + (size_t)arow0 * K + skc) : nullptr;
    const float* A2b1 = FUSE ? (A2 + (size_t)arow1 * K + skc) : nullptr;
    const float* Wb0 = W + (size_t)(n0 + srow) * K + skc;
    const float* Wb1 = W + (size_t)(n0 + srow + 64) * K + skc;

    float acc[8][8] = {};

    for (int k0 = 0; k0 < K; k0 += 16) {
        float4 a0 = *(const float4*)(Ab0 + k0);
        float4 a1 = *(const float4*)(Ab1 + k0);
        float4 w0 = *(const float4*)(Wb0 + k0);
        float4 w1 = *(const float4*)(Wb1 + k0);
        if (FUSE) {
            float4 e0 = *(const float4*)(A2b0 + k0);
            float4 e1 = *(const float4*)(A2b1 + k0);
            a0.x += e0.x; a0.y += e0.y; a0.z += e0.z; a0.w += e0.w;
            a1.x += e1.x; a1.y += e1.y; a1.z += e1.z; a1.w += e1.w;
        }
        __syncthreads();
        As[skc+0][srow] = a0.x; As[skc+1][srow] = a0.y; As[skc+2][srow] = a0.z; As[skc+3][srow] = a0.w;
        As[skc+0][srow+64] = a1.x; As[skc+1][srow+64] = a1.y; As[skc+2][srow+64] = a1.z; As[skc+3][srow+64] = a1.w;
        Ws[skc+0][srow] = w0.x; Ws[skc+1][srow] = w0.y; Ws[skc+2][srow] = w0.z; Ws[skc+3][srow] = w0.w;
        Ws[skc+0][srow+64] = w1.x; Ws[skc+1][srow+64] = w1.y; Ws[skc+2][srow+64] = w1.z; Ws[skc+3][srow+64] = w1.w;
        __syncthreads();
        #pragma unroll
        for (int kk = 0; kk < 16; ++kk) {
            float av[8], bv[8];
            *(float4*)&av[0] = *(const float4*)&As[kk][ty*8];
            *(float4*)&av[4] = *(const float4*)&As[kk][ty*8+4];
            *(float4*)&bv[0] = *(const float4*)&Ws[kk][tx*8];
            *(float4*)&bv[4] = *(const float4*)&Ws[kk][tx*8+4];
            #pragma unroll
            for (int i = 0; i < 8; ++i)
                #pragma unroll
                for (int j = 0; j < 8; ++j)
                    acc[i][j] = fmaf(av[i], bv[j], acc[i][j]);
        }
    }

    float bn[8];
    #pragma unroll
    for (int j = 0; j < 8; ++j) bn[j] = bias[n0 + tx*8 + j];

    #pragma unroll
    for (int i = 0; i < 8; ++i) {
        int m = m0 + ty*8 + i;
        if (m >= M) continue;
        float o[8];
        #pragma unroll
        for (int j = 0; j < 8; ++j) {
            float v = acc[i][j] + bn[j];
            if (RELU) v = fmaxf(v, 0.0f);
            o[j] = v;
        }
        float* cp = Cmat + (size_t)m * N + n0 + tx*8;
        *(float4*)cp       = *(float4*)&o[0];
        *(float4*)(cp + 4) = *(float4*)&o[4];
    }
}

// ============ ROWS GEMM: 64x128 tile, 4x8 micro (better grid fill for M=2400) ============
template<int RELU>
__global__ __launch_bounds__(256) void gemm64_kernel(
    const float* __restrict__ A,
    const float* __restrict__ W, const float* __restrict__ bias,
    float* __restrict__ Cmat, int M, int N, int K)
{
    __shared__ float As[16][68];
    __shared__ float Ws[16][132];
    const int tid = threadIdx.x;
    const int m0 = blockIdx.x * 64;
    const int n0 = blockIdx.y * 128;
    const int tx = tid & 15, ty = tid >> 4;

    const int ar  = tid >> 2;
    const int kca = (tid & 3) * 4;
    const int wr  = tid >> 1;
    const int kcw = (tid & 1) * 8;

    const int arow = min(m0 + ar, M - 1);
    const float* Ab = A + (size_t)arow * K + kca;
    const float* Wb = W + (size_t)(n0 + wr) * K + kcw;

    float acc[4][8] = {};

    for (int k0 = 0; k0 < K; k0 += 16) {
        float4 a0 = *(const float4*)(Ab + k0);
        float4 w0 = *(const float4*)(Wb + k0);
        float4 w1 = *(const float4*)(Wb + k0 + 4);
        __syncthreads();
        As[kca+0][ar] = a0.x; As[kca+1][ar] = a0.y; As[kca+2][ar] = a0.z; As[kca+3][ar] = a0.w;
        Ws[kcw+0][wr] = w0.x; Ws[kcw+1][wr] = w0.y; Ws[kcw+2][wr] = w0.z; Ws[kcw+3][wr] = w0.w;
        Ws[kcw+4][wr] = w1.x; Ws[kcw+5][wr] = w1.y; Ws[kcw+6][wr] = w1.z; Ws[kcw+7][wr] = w1.w;
        __syncthreads();
        #pragma unroll
        for (int kk = 0; kk < 16; ++kk) {
            float av[4], bv[8];
            *(float4*)&av[0] = *(const float4*)&As[kk][ty*4];
            *(float4*)&bv[0] = *(const float4*)&Ws[kk][tx*8];
            *(float4*)&bv[4] = *(const float4*)&Ws[kk][tx*8+4];
            #pragma unroll
            for (int i = 0; i < 4; ++i)
                #pragma unroll
                for (int j = 0; j < 8; ++j)
                    acc[i][j] = fmaf(av[i], bv[j], acc[i][j]);
        }
    }

    float bn[8];
    #pragma unroll
    for (int j = 0; j < 8; ++j) bn[j] = bias[n0 + tx*8 + j];

    #pragma unroll
    for (int i = 0; i < 4; ++i) {
        int m = m0 + ty*4 + i;
        if (m >= M) continue;
        float o[8];
        #pragma unroll
        for (int j = 0; j < 8; ++j) {
            float v = acc[i][j] + bn[j];
            if (RELU) v = fmaxf(v, 0.0f);
            o[j] = v;
        }
        float* cp = Cmat + (size_t)m * N + n0 + tx*8;
        *(float4*)cp       = *(float4*)&o[0];
        *(float4*)(cp + 4) = *(float4*)&o[4];
    }
}

// ============ LayerNorm ============
__global__ __launch_bounds__(256) void ln_kernel(const float* __restrict__ Xa, const float* __restrict__ Xb,
    const float* __restrict__ g, const float* __restrict__ beta, float* __restrict__ out, int rows)
{
    int wid  = (blockIdx.x * blockDim.x + threadIdx.x) >> 6;
    int lane = threadIdx.x & 63;
    if (wid >= rows) return;
    float4 x = ((const float4*)(Xa + (size_t)wid * C_))[lane];
    float4 y = ((const float4*)(Xb + (size_t)wid * C_))[lane];
    x.x += y.x; x.y += y.y; x.z += y.z; x.w += y.w;
    float s = x.x + x.y + x.z + x.w;
    for (int d = 32; d > 0; d >>= 1) s += __shfl_xor(s, d);
    float mean = s * (1.0f / C_);
    float dx = x.x - mean, dy = x.y - mean, dz = x.z - mean, dw = x.w - mean;
    float v = dx*dx + dy*dy + dz*dz + dw*dw;
    for (int d = 32; d > 0; d >>= 1) v += __shfl_xor(v, d);
    float rstd = 1.0f / sqrtf(v * (1.0f / C_) + 1e-5f);
    float4 gg = ((const float4*)g)[lane];
    float4 bb = ((const float4*)beta)[lane];
    float4 o;
    o.x = dx * rstd * gg.x + bb.x;
    o.y = dy * rstd * gg.y + bb.y;
    o.z = dz * rstd * gg.z + bb.z;
    o.w = dw * rstd * gg.w + bb.w;
    ((float4*)(out + (size_t)wid * C_))[lane] = o;
}

// ============ x broadcast ============
__global__ void xbcast_kernel(const float* __restrict__ qf, float* __restrict__ x) {
    __shared__ float tile[32][33];
    int b  = blockIdx.z;
    int p0 = blockIdx.x * 32, c0 = blockIdx.y * 32;
    int tx = threadIdx.x, ty = threadIdx.y;
    float v = 0.0f;
    if (p0 + tx < P_) v = qf[((size_t)b * C_ + c0 + ty) * P_ + p0 + tx];
    tile[ty][tx] = v;
    __syncthreads();
    int p = p0 + ty;
    if (p < P_) {
        float val = tile[tx][ty];
        #pragma unroll
        for (int vv = 0; vv < V_; ++vv)
            x[(((size_t)(b*V_ + vv) * P_) + p) * C_ + c0 + tx] = val;
    }
}

// ============ out = x + broadcast_over_V(peq) ============
__global__ void bcast_add_kernel(const float* __restrict__ x, const float* __restrict__ peq, float* __restrict__ out) {
    int g = blockIdx.x * blockDim.x + threadIdx.x;
    const int total = ROWS_ * C_ / 4;
    if (g >= total) return;
    int c4 = g & 63;
    int rest = g >> 6;
    int p  = rest % P_;
    int bv = rest / P_;
    int b  = bv / V_;
    float4 xv = ((const float4*)x)[g];
    float4 pv = ((const float4*)peq)[((size_t)(b*P_ + p)) * 64 + c4];
    float4 o; o.x = xv.x + pv.x; o.y = xv.y + pv.y; o.z = xv.z + pv.z; o.w = xv.w + pv.w;
    ((float4*)out)[g] = o;
}

// ============ attention: tile-batched online softmax ============
__global__ __launch_bounds__(256) void attn_kernel(
    const float* __restrict__ Q, int qstride,
    const float* __restrict__ Kp, int kstride,
    const float* __restrict__ Vp, int vstride,
    const float* __restrict__ biasNeg,
    float* __restrict__ pAcc, float* __restrict__ pML,
    int NK, int S, float scale)
{
    int split = blockIdx.x, bvh = blockIdx.y;
    int bv = bvh >> 3, h = bvh & 7;
    int p = threadIdx.x;
    bool act = p < P_;
    int per = (NK + S - 1) / S;
    int k0 = split * per;
    int k1 = min(NK, k0 + per);

    __shared__ float Ks[32][36];
    __shared__ float Vs[32][36];
    __shared__ float Bs[32];

    float q[32];
    const float* qrow = Q + ((size_t)bv * P_ + (act ? p : 0)) * qstride + h * 32;
    #pragma unroll
    for (int j = 0; j < 32; j += 4) {
        float4 t = *(const float4*)(qrow + j);
        q[j] = t.x; q[j+1] = t.y; q[j+2] = t.z; q[j+3] = t.w;
    }
    float m = -INFINITY, l = 0.0f;
    float acc[32] = {};

    for (int kt = k0; kt < k1; kt += 32) {
        int kmax = min(32, k1 - kt);
        __syncthreads();
        {
            int t = threadIdx.x;
            int key = t >> 3, f = (t & 7) << 2;
            if (key < kmax) {
                const float* kr = Kp + ((size_t)bv * NK + kt + key) * kstride + h*32 + f;
                *(float4*)&Ks[key][f] = *(const float4*)kr;
                const float* vr = Vp + ((size_t)bv * NK + kt + key) * vstride + h*32 + f;
                *(float4*)&Vs[key][f] = *(const float4*)vr;
            } else {
                float4 z = make_float4(0.f, 0.f, 0.f, 0.f);
                *(float4*)&Ks[key][f] = z;
                *(float4*)&Vs[key][f] = z;
            }
            if (t < 32) Bs[t] = (t < kmax) ? (biasNeg ? biasNeg[bv * P_ + kt + t] : 0.0f) : -INFINITY;
        }
        __syncthreads();
        if (act) {
            // pass 1: 32 scores into registers
            float sc[32];
            #pragma unroll
            for (int k = 0; k < 32; ++k) {
                const float4* k4 = (const float4*)&Ks[k][0];
                float s0 = 0, s1 = 0, s2 = 0, s3 = 0;
                #pragma unroll
                for (int jj = 0; jj < 8; ++jj) {
                    float4 kv = k4[jj];
                    s0 = fmaf(q[4*jj+0], kv.x, s0);
                    s1 = fmaf(q[4*jj+1], kv.y, s1);
                    s2 = fmaf(q[4*jj+2], kv.z, s2);
                    s3 = fmaf(q[4*jj+3], kv.w, s3);
                }
                sc[k] = ((s0 + s1) + (s2 + s3)) * scale + Bs[k];
            }
            // tile max + single rescale
            float tm = sc[0];
            #pragma unroll
            for (int k = 1; k < 32; ++k) tm = fmaxf(tm, sc[k]);
            float nm = fmaxf(m, tm);
            float corr = __expf(m - nm);     // m=-INF -> 0, safe
            m = nm;
            l *= corr;
            #pragma unroll
            for (int j = 0; j < 32; ++j) acc[j] *= corr;
            // pass 2: exp + PV
            #pragma unroll
            for (int k = 0; k < 32; ++k) {
                float pr = __expf(sc[k] - nm);   // padded keys: exp(-INF)=0 exactly
                l += pr;
                const float4* v4 = (const float4*)&Vs[k][0];
                #pragma unroll
                for (int jj = 0; jj < 8; ++jj) {
                    float4 vv = v4[jj];
                    acc[4*jj+0] = fmaf(pr, vv.x, acc[4*jj+0]);
                    acc[4*jj+1] = fmaf(pr, vv.y, acc[4*jj+1]);
                    acc[4*jj+2] = fmaf(pr, vv.z, acc[4*jj+2]);
                    acc[4*jj+3] = fmaf(pr, vv.w, acc[4*jj+3]);
                }
            }
        }
    }
    if (act) {
        size_t base = ((size_t)bvh * S + split) * 32 * P_ + p;
        #pragma unroll
        for (int j = 0; j < 32; ++j) pAcc[base + (size_t)j * P_] = acc[j];
        size_t mb = ((size_t)bvh * S + split) * 2 * P_ + p;
        pML[mb] = m; pML[mb + P_] = l;
    }
}

// ============ combine split partials ============
template<int S>
__global__ void attn_combine_kernel(const float* __restrict__ pAcc, const float* __restrict__ pML,
                                    float* __restrict__ Out)
{
    int g = blockIdx.x * blockDim.x + threadIdx.x;
    if (g >= BVH_ * P_) return;
    int p = g % P_;
    int bvh = g / P_;
    int bv = bvh >> 3, h = bvh & 7;
    float mg = -INFINITY;
    #pragma unroll
    for (int s = 0; s < S; ++s) mg = fmaxf(mg, pML[((size_t)bvh * S + s) * 2 * P_ + p]);
    float w[S];
    float L = 0.0f;
    #pragma unroll
    for (int s = 0; s < S; ++s) {
        float ms = pML[((size_t)bvh * S + s) * 2 * P_ + p];
        float ls = pML[((size_t)bvh * S + s) * 2 * P_ + P_ + p];
        float ws = __expf(ms - mg);
        w[s] = ws;
        L = fmaf(ls, ws, L);
    }
    float invL = 1.0f / L;
    float* orow = Out + ((size_t)bv * P_ + p) * C_ + h * 32;
    #pragma unroll
    for (int j = 0; j < 32; ++j) {
        float acc = 0.0f;
        #pragma unroll
        for (int s = 0; s < S; ++s)
            acc = fmaf(pAcc[(((size_t)bvh * S + s) * 32 + j) * P_ + p], w[s], acc);
        orow[j] = acc * invL;
    }
}

// ============ aggregation over views (+transposed copy for head) ============
__global__ void agg_kernel(const float* __restrict__ x, const float* __restrict__ actF,
                           float* __restrict__ qf, float* __restrict__ qft, float* __restrict__ qf_out) {
    int bp = blockIdx.x;
    int b = bp / P_, p = bp % P_;
    int c = threadIdx.x;
    float sum = 0.0f, cnt = 0.0f;
    #pragma unroll
    for (int v = 0; v < V_; ++v) {
        float a = actF[(b*V_ + v) * P_ + p];
        cnt += a;
        sum = fmaf(a, x[(((size_t)(b*V_ + v)) * P_ + p) * C_ + c], sum);
    }
    float r = sum / (cnt + 1e-4f);
    qf[((size_t)b * C_ + c) * P_ + p] = r;
    qft[((size_t)b * P_ + p) * C_ + c] = r;
    if (qf_out) qf_out[((size_t)b * C_ + c) * P_ + p] = r;
}

// ============ fused head: h1 = relu(W1 qcol + b1); out3 = W2 h1 + b2 + qpos ============
__global__ __launch_bounds__(256) void head_kernel(
    const float* __restrict__ w1, const float* __restrict__ b1,
    const float* __restrict__ w2, const float* __restrict__ b2,
    const float* __restrict__ qft, const float* __restrict__ qpos_in,
    float* __restrict__ qpos_ws, float* __restrict__ out, int layer)
{
    int bp = blockIdx.x;
    int b = bp / P_, p = bp % P_;
    int tid = threadIdx.x;
    __shared__ float qcol[C_];
    __shared__ float h1s[C_];
    qcol[tid] = qft[((size_t)b * P_ + p) * C_ + tid];
    __syncthreads();
    float s = b1[tid];
    const float* wr = w1 + (size_t)tid * C_;
    #pragma unroll 8
    for (int c = 0; c < C_; ++c) s = fmaf(wr[c], qcol[c], s);
    h1s[tid] = fmaxf(s, 0.0f);
    __syncthreads();
    int grp = tid >> 6, lane = tid & 63;
    if (grp < 3) {
        float part = 0.0f;
        #pragma unroll
        for (int c = 0; c < 4; ++c)
            part = fmaf(w2[grp * C_ + lane + c*64], h1s[lane + c*64], part);
        for (int d = 32; d > 0; d >>= 1) part += __shfl_xor(part, d);
        if (lane == 0) {
            float val = part + b2[grp] + qpos_in[((size_t)b * P_ + p) * 3 + grp];
            qpos_ws[((size_t)b * P_ + p) * 3 + grp] = val;
            if (grp == 2) {
                out[OO_HEIGHTS + (size_t)(layer * B_ + b) * P_ + p] = val;
                if (layer == L_ - 1)
                    out[OO_QPOS + ((size_t)b * P_ + p) * 3 + 2] = val;
            } else {
                float cbev = (val + 54.0f) / 108.0f * 180.0f;
                float* centers = out + OO_CENTERS + ((size_t)(layer * B_ + b) * 2) * P_;
                centers[grp * P_ + p] = cbev;
                if (layer == L_ - 1) {
                    out[OO_QPOS + ((size_t)b * P_ + p) * 3 + grp] = val;
                    out[OO_POSBEV + ((size_t)b * P_ + p) * 2 + grp] = cbev;
                }
            }
        }
    }
}

// =====================================================================
extern "C" void kernel_launch(void* const* d_in, const int* in_sizes, int n_in,
                              void* d_out, int out_size, void* d_ws, size_t ws_size,
                              hipStream_t stream) {
    const float* in_qfeat = (const float*)d_in[0];
    const float* in_qpos  = (const float*)d_in[1];
    const int*   in_qvm   = (const int*)d_in[2];
    const float* in_f0    = (const float*)d_in[3];
    const float* in_f1    = (const float*)d_in[4];
    const float* in_pos   = (const float*)d_in[5];
    const float* in_l2i   = (const float*)d_in[6];
    const int*   in_hw    = (const int*)d_in[7];
    const float* qpos_w1  = (const float*)d_in[8];
    const float* qpos_b1  = (const float*)d_in[9];
    const float* qpos_w2  = (const float*)d_in[10];
    const float* qpos_b2  = (const float*)d_in[11];
    const float* kpos_w1  = (const float*)d_in[12];
    const float* kpos_b1  = (const float*)d_in[13];
    const float* kpos_w2  = (const float*)d_in[14];
    const float* kpos_b2  = (const float*)d_in[15];
    const float* sa_in_w  = (const float*)d_in[16];
    const float* sa_in_b  = (const float*)d_in[17];
    const float* sa_out_w = (const float*)d_in[18];
    const float* sa_out_b = (const float*)d_in[19];
    const float* ca_in_w  = (const float*)d_in[20];
    const float* ca_in_b  = (const float*)d_in[21];
    const float* ca_out_w = (const float*)d_in[22];
    const float* ca_out_b = (const float*)d_in[23];
    const float* ffn_w1   = (const float*)d_in[24];
    const float* ffn_b1   = (const float*)d_in[25];
    const float* ffn_w2   = (const float*)d_in[26];
    const float* ffn_b2   = (const float*)d_in[27];
    const float* n1_g     = (const float*)d_in[28];
    const float* n1_b     = (const float*)d_in[29];
    const float* n2_g     = (const float*)d_in[30];
    const float* n2_b     = (const float*)d_in[31];
    const float* n3_g     = (const float*)d_in[32];
    const float* n3_b     = (const float*)d_in[33];
    const float* head_w1  = (const float*)d_in[34];
    const float* head_b1  = (const float*)d_in[35];
    const float* head_w2  = (const float*)d_in[36];
    const float* head_b2  = (const float*)d_in[37];

    float* ws   = (float*)d_ws;
    float* KEYS = ws + O_KEYS;
    float* CAM  = ws + O_CAM;
    float* PEK  = ws + O_PEK;
    float* HID  = ws + O_HID;
    float* KVP  = ws + O_KVP;
    float* PEQH = ws + O_PEQH;
    float* PEQ  = ws + O_PEQ;
    float* X    = ws + O_X;
    float* QKV  = ws + O_QKV;
    float* SAIN = ws + O_SAIN;
    float* ATT  = ws + O_ATT;
    float* QPROJ= ws + O_QPROJ;
    float* PROJ = ws + O_PROJ;
    float* TMP  = ws + O_TMP;
    float* FFNH = ws + O_FFNH;
    float* QF   = ws + O_QF;
    float* QFT  = ws + O_QFT;
    float* QPOS = ws + O_QPOS;
    float* ACTF = ws + O_ACTF;
    float* ACTN = ws + O_ACTN;
    float* INV  = ws + O_INV;
    float* PML  = ws + O_PML;
    float* PACC = ws + O_PACC;
    float* OUT  = (float*)d_out;

    const float scale = 0.17677669529663687f;   // 1/sqrt(32)

    // ---- one-time precompute ----
    inv4_kernel<<<1, 64, 0, stream>>>(in_l2i, INV);
    cam_kernel<<<(BV_*N_*D_ + 255)/256, 256, 0, stream>>>(in_pos, in_hw, INV, CAM);
    transpose_keys_kernel<<<dim3(HW0T/32, C_/32, BV_), dim3(32,32), 0, stream>>>(in_f0, KEYS, HW0T, 0);
    transpose_keys_kernel<<<dim3(HW1T/32, C_/32, BV_), dim3(32,32), 0, stream>>>(in_f1, KEYS, HW1T, HW0T);
    mask_kernel<<<BV_, 256, 0, stream>>>(in_qvm, ACTF, ACTN);

    const int MT_NK  = NKTOT / 128;         // 330
    const int MT64_R = (ROWS_ + 63) / 64;   // 38

    for (int l = 0; l < L_; ++l) {
        const float* qf_src   = (l == 0) ? in_qfeat : QF;
        const float* qpos_src = (l == 0) ? in_qpos  : QPOS;

        // pe_q MLP (400 rows): 3 -> 256 relu -> 256 (small kernel)
        gemm_kernel<1,0><<<dim3(4,7), 256, 0, stream>>>(qpos_src, nullptr, qpos_w1 + l*C_*3, qpos_b1 + l*C_, PEQH, 400, C_, 3);
        gemm_kernel<0,0><<<dim3(4,7), 256, 0, stream>>>(PEQH, nullptr, qpos_w2 + l*C_*C_, qpos_b2 + l*C_, PEQ, 400, C_, C_);

        // pe_k MLP (42240 rows)
        gemm128_kernel<1,0><<<dim3(MT_NK, 2), 256, 0, stream>>>(CAM, nullptr, kpos_w1 + l*C_*96, kpos_b1 + l*C_, HID, NKTOT, C_, 96);
        gemm128_kernel<0,0><<<dim3(MT_NK, 2), 256, 0, stream>>>(HID, nullptr, kpos_w2 + l*C_*C_, kpos_b2 + l*C_, PEK, NKTOT, C_, C_);

        // x = broadcast(q_feat); qkv = x + pe_q
        xbcast_kernel<<<dim3(7, 8, B_), dim3(32,32), 0, stream>>>(qf_src, X);
        bcast_add_kernel<<<600, 256, 0, stream>>>(X, PEQ, QKV);

        // --- self attention ---
        gemm64_kernel<0><<<dim3(MT64_R, 6), 256, 0, stream>>>(QKV, sa_in_w + l*768*C_, sa_in_b + l*768, SAIN, ROWS_, 768, C_);
        attn_kernel<<<dim3(8, BVH_), 256, 0, stream>>>(SAIN, 768, SAIN + 256, 768, SAIN + 512, 768, ACTN, PACC, PML, P_, 8, scale);
        attn_combine_kernel<8><<<(BVH_*P_)/256, 256, 0, stream>>>(PACC, PML, ATT);
        gemm64_kernel<0><<<dim3(MT64_R, 2), 256, 0, stream>>>(ATT, sa_out_w + l*C_*C_, sa_out_b + l*C_, PROJ, ROWS_, C_, C_);
        ln_kernel<<<600, 256, 0, stream>>>(X, PROJ, n1_g + l*C_, n1_b + l*C_, X, ROWS_);

        // --- cross attention ---
        bcast_add_kernel<<<600, 256, 0, stream>>>(X, PEQ, TMP);
        gemm64_kernel<0><<<dim3(MT64_R, 2), 256, 0, stream>>>(TMP, ca_in_w + l*768*C_, ca_in_b + l*768, QPROJ, ROWS_, C_, C_);
        gemm128_kernel<0,1><<<dim3(MT_NK, 4), 256, 0, stream>>>(KEYS, PEK, ca_in_w + l*768*C_ + C_*C_, ca_in_b + l*768 + C_, KVP, NKTOT, 512, C_);
        attn_kernel<<<dim3(8, BVH_), 256, 0, stream>>>(QPROJ, 256, KVP, 512, KVP + 256, 512, nullptr, PACC, PML, N_, 8, scale);
        attn_combine_kernel<8><<<(BVH_*P_)/256, 256, 0, stream>>>(PACC, PML, ATT);
        gemm64_kernel<0><<<dim3(MT64_R, 2), 256, 0, stream>>>(ATT, ca_out_w + l*C_*C_, ca_out_b + l*C_, PROJ, ROWS_, C_, C_);
        ln_kernel<<<600, 256, 0, stream>>>(X, PROJ, n2_g + l*C_, n2_b + l*C_, X, ROWS_);

        // --- FFN ---
        gemm64_kernel<1><<<dim3(MT64_R, 8), 256, 0, stream>>>(X, ffn_w1 + l*F_*C_, ffn_b1 + l*F_, FFNH, ROWS_, F_, C_);
        gemm64_kernel<0><<<dim3(MT64_R, 2), 256, 0, stream>>>(FFNH, ffn_w2 + l*C_*F_, ffn_b2 + l*C_, PROJ, ROWS_, C_, F_);
        ln_kernel<<<600, 256, 0, stream>>>(X, PROJ, n3_g + l*C_, n3_b + l*C_, X, ROWS_);

        // --- aggregate over views ---
        agg_kernel<<<B_*P_, 256, 0, stream>>>(X, ACTF, QF, QFT, (l == L_-1) ? (OUT + OO_QFEAT) : nullptr);

        // --- fused head ---
        head_kernel<<<B_*P_, 256, 0, stream>>>(head_w1, head_b1, head_w2, head_b2,
                                               QFT, qpos_src, QPOS, OUT, l);
    }
}